// Round 1
// baseline (2641.406 us; speedup 1.0000x reference)
//
#include <hip/hip_runtime.h>

typedef unsigned short u16;
typedef unsigned int u32;

#define NB 8
#define NCH 192
#define NC3 576
#define NHW 16384
#define NHEADS 8

__device__ __forceinline__ float bf2f(u32 h) {
  return __uint_as_float(h << 16);
}
__device__ __forceinline__ u16 f2bf(float f) {
  u32 u = __float_as_uint(f);
  u = (u + 0x7fffu + ((u >> 16) & 1u)) >> 16;
  return (u16)u;
}

#define FMA4(ac, s, v)            \
  ac.x = fmaf(s, v.x, ac.x);      \
  ac.y = fmaf(s, v.y, ac.y);      \
  ac.z = fmaf(s, v.z, ac.z);      \
  ac.w = fmaf(s, v.w, ac.w)

#define SEL4(vec, kk) ((kk) == 0 ? (vec).x : (kk) == 1 ? (vec).y : (kk) == 2 ? (vec).z : (vec).w)

// ---------------------------------------------------------------------------
// conv1x1: out[b][o][n] = sum_k w[o][k] * x[b][k][n];  M=576, K=192, N=16384
// BM=64, BN=128, K chunked by 96. fp32 in, bf16 out.
// ---------------------------------------------------------------------------
__global__ __launch_bounds__(256) void conv1x1_kernel(
    const float* __restrict__ x, const float* __restrict__ w, u16* __restrict__ out) {
  __shared__ float Wt[64][100];   // pad 96->100 (bank shift 4)
  __shared__ float Xt[96][132];   // pad 128->132
  const int nbase = blockIdx.x * 128;
  const int obase = blockIdx.y * 64;
  const int b = blockIdx.z;
  const int tid = threadIdx.x;
  const int tx = tid & 15, ty = tid >> 4;

  float4 accL[4], accH[4];
#pragma unroll
  for (int i = 0; i < 4; ++i) {
    accL[i] = make_float4(0.f, 0.f, 0.f, 0.f);
    accH[i] = make_float4(0.f, 0.f, 0.f, 0.f);
  }

  for (int kb = 0; kb < 192; kb += 96) {
    for (int idx = tid; idx < 64 * 24; idx += 256) {
      int r = idx / 24, c4 = (idx % 24) * 4;
      *(float4*)&Wt[r][c4] = *(const float4*)&w[(obase + r) * 192 + kb + c4];
    }
    for (int idx = tid; idx < 96 * 32; idx += 256) {
      int r = idx >> 5, c4 = (idx & 31) * 4;
      *(float4*)&Xt[r][c4] = *(const float4*)&x[((size_t)b * NCH + kb + r) * NHW + nbase + c4];
    }
    __syncthreads();
    for (int k4 = 0; k4 < 24; ++k4) {
      float4 a0 = *(const float4*)&Wt[ty * 4 + 0][k4 * 4];
      float4 a1 = *(const float4*)&Wt[ty * 4 + 1][k4 * 4];
      float4 a2 = *(const float4*)&Wt[ty * 4 + 2][k4 * 4];
      float4 a3 = *(const float4*)&Wt[ty * 4 + 3][k4 * 4];
#pragma unroll
      for (int kk = 0; kk < 4; ++kk) {
        float4 b0 = *(const float4*)&Xt[k4 * 4 + kk][tx * 8];
        float4 b1 = *(const float4*)&Xt[k4 * 4 + kk][tx * 8 + 4];
        float av0 = SEL4(a0, kk), av1 = SEL4(a1, kk), av2 = SEL4(a2, kk), av3 = SEL4(a3, kk);
        FMA4(accL[0], av0, b0); FMA4(accH[0], av0, b1);
        FMA4(accL[1], av1, b0); FMA4(accH[1], av1, b1);
        FMA4(accL[2], av2, b0); FMA4(accH[2], av2, b1);
        FMA4(accL[3], av3, b0); FMA4(accH[3], av3, b1);
      }
    }
    __syncthreads();
  }
#pragma unroll
  for (int i = 0; i < 4; ++i) {
    u32 p0 = (u32)f2bf(accL[i].x) | ((u32)f2bf(accL[i].y) << 16);
    u32 p1 = (u32)f2bf(accL[i].z) | ((u32)f2bf(accL[i].w) << 16);
    u32 p2 = (u32)f2bf(accH[i].x) | ((u32)f2bf(accH[i].y) << 16);
    u32 p3 = (u32)f2bf(accH[i].z) | ((u32)f2bf(accH[i].w) << 16);
    u16* dst = out + ((size_t)b * NC3 + obase + ty * 4 + i) * NHW + nbase + tx * 8;
    *(uint4*)dst = make_uint4(p0, p1, p2, p3);
  }
}

// ---------------------------------------------------------------------------
// depthwise 3x3, SAME pad, cross-correlation. bf16 in/out, fp32 weights.
// ---------------------------------------------------------------------------
__global__ __launch_bounds__(256) void dwconv_kernel(
    const u16* __restrict__ in, const float* __restrict__ wdw, u16* __restrict__ out) {
  size_t gid = (size_t)blockIdx.x * 256 + threadIdx.x;
  const int xx = (int)(gid & 127);
  const int yy = (int)((gid >> 7) & 127);
  const int bc = (int)(gid >> 14);
  const int c = bc % NC3;
  const u16* p = in + ((size_t)bc << 14);
  const float* wc = wdw + c * 9;
  float s = 0.f;
#pragma unroll
  for (int dy = -1; dy <= 1; ++dy) {
    const int y2 = yy + dy;
    if ((unsigned)y2 < 128u) {
      const u16* row = p + (y2 << 7);
#pragma unroll
      for (int dx = -1; dx <= 1; ++dx) {
        const int x2 = xx + dx;
        if ((unsigned)x2 < 128u)
          s = fmaf(wc[(dy + 1) * 3 + (dx + 1)], bf2f(row[x2]), s);
      }
    }
  }
  out[gid] = f2bf(s);
}

// ---------------------------------------------------------------------------
// row L2 norms for q1,q2,k1,k2.  norms[t][b][c], t in {q1,q2,k1,k2}
// ---------------------------------------------------------------------------
__global__ __launch_bounds__(256) void norms_kernel(
    const u16* __restrict__ qkv1, const u16* __restrict__ qkv2, float* __restrict__ norms) {
  const int r = blockIdx.x;  // [0, 4*8*192)
  const int t = r / (NB * NCH);
  const int rem = r % (NB * NCH);
  const int b = rem / NCH, c = rem % NCH;
  const u16* base = (t == 0 || t == 2) ? qkv1 : qkv2;
  const u16* p = base + (((size_t)b * NC3 + (t >= 2 ? 192 : 0) + c) << 14);
  const int tid = threadIdx.x;
  float s = 0.f;
  for (int it = 0; it < 16; ++it) {
    uint2 v = *(const uint2*)(p + (it * 256 + tid) * 4);
    float f0 = bf2f(v.x & 0xffff), f1 = bf2f(v.x >> 16);
    float f2 = bf2f(v.y & 0xffff), f3 = bf2f(v.y >> 16);
    s += f0 * f0 + f1 * f1 + f2 * f2 + f3 * f3;
  }
#pragma unroll
  for (int off = 32; off > 0; off >>= 1) s += __shfl_down(s, off, 64);
  __shared__ float red[4];
  if ((tid & 63) == 0) red[tid >> 6] = s;
  __syncthreads();
  if (tid == 0) norms[r] = sqrtf(red[0] + red[1] + red[2] + red[3]);
}

// ---------------------------------------------------------------------------
// Gram partials: rows=[q1;q2] (48), cols=[k1;k2] (48), per (b,h,nchunk of 1024)
// gp[((b*8+h)*16+nc)][48][48]
// ---------------------------------------------------------------------------
__global__ __launch_bounds__(256) void gram_partial_kernel(
    const u16* __restrict__ qkv1, const u16* __restrict__ qkv2, float* __restrict__ gp) {
  __shared__ float Qt[48][260];
  __shared__ float Kt[48][260];
  const int nc = blockIdx.x, h = blockIdx.y, b = blockIdx.z;
  const int tid = threadIdx.x;
  const int tx = tid & 15, ty = tid >> 4;
  float acc[3][3] = {};
  for (int sc = 0; sc < 4; ++sc) {
    const int noff = nc * 1024 + sc * 256;
    for (int idx = tid; idx < 48 * 64; idx += 256) {
      int r = idx >> 6, c4 = (idx & 63) * 4;
      const u16* pq = (r < 24) ? qkv1 + (((size_t)b * NC3 + h * 24 + r) << 14)
                               : qkv2 + (((size_t)b * NC3 + h * 24 + r - 24) << 14);
      uint2 v = *(const uint2*)(pq + noff + c4);
      Qt[r][c4 + 0] = bf2f(v.x & 0xffff);
      Qt[r][c4 + 1] = bf2f(v.x >> 16);
      Qt[r][c4 + 2] = bf2f(v.y & 0xffff);
      Qt[r][c4 + 3] = bf2f(v.y >> 16);
      const u16* pk = (r < 24) ? qkv1 + (((size_t)b * NC3 + 192 + h * 24 + r) << 14)
                               : qkv2 + (((size_t)b * NC3 + 192 + h * 24 + r - 24) << 14);
      uint2 w2 = *(const uint2*)(pk + noff + c4);
      Kt[r][c4 + 0] = bf2f(w2.x & 0xffff);
      Kt[r][c4 + 1] = bf2f(w2.x >> 16);
      Kt[r][c4 + 2] = bf2f(w2.y & 0xffff);
      Kt[r][c4 + 3] = bf2f(w2.y >> 16);
    }
    __syncthreads();
    for (int k4 = 0; k4 < 64; ++k4) {
      float4 qa0 = *(const float4*)&Qt[ty * 3 + 0][k4 * 4];
      float4 qa1 = *(const float4*)&Qt[ty * 3 + 1][k4 * 4];
      float4 qa2 = *(const float4*)&Qt[ty * 3 + 2][k4 * 4];
      float4 kb0 = *(const float4*)&Kt[tx * 3 + 0][k4 * 4];
      float4 kb1 = *(const float4*)&Kt[tx * 3 + 1][k4 * 4];
      float4 kb2 = *(const float4*)&Kt[tx * 3 + 2][k4 * 4];
#pragma unroll
      for (int kk = 0; kk < 4; ++kk) {
        float q0 = SEL4(qa0, kk), q1 = SEL4(qa1, kk), q2 = SEL4(qa2, kk);
        float c0 = SEL4(kb0, kk), c1 = SEL4(kb1, kk), c2 = SEL4(kb2, kk);
        acc[0][0] = fmaf(q0, c0, acc[0][0]);
        acc[0][1] = fmaf(q0, c1, acc[0][1]);
        acc[0][2] = fmaf(q0, c2, acc[0][2]);
        acc[1][0] = fmaf(q1, c0, acc[1][0]);
        acc[1][1] = fmaf(q1, c1, acc[1][1]);
        acc[1][2] = fmaf(q1, c2, acc[1][2]);
        acc[2][0] = fmaf(q2, c0, acc[2][0]);
        acc[2][1] = fmaf(q2, c1, acc[2][1]);
        acc[2][2] = fmaf(q2, c2, acc[2][2]);
      }
    }
    __syncthreads();
  }
  float* dst = gp + ((((size_t)b * 8 + h) * 16 + nc) * 2304);
#pragma unroll
  for (int i = 0; i < 3; ++i)
#pragma unroll
    for (int j = 0; j < 3; ++j)
      dst[(ty * 3 + i) * 48 + tx * 3 + j] = acc[i][j];
}

__global__ __launch_bounds__(256) void gram_reduce_kernel(
    const float* __restrict__ gp, float* __restrict__ G) {
  const int bh = blockIdx.x;
  for (int e = threadIdx.x; e < 2304; e += 256) {
    float s = 0.f;
    for (int p = 0; p < 16; ++p) s += gp[((size_t)bh * 16 + p) * 2304 + e];
    G[(size_t)bh * 2304 + e] = s;
  }
}

// ---------------------------------------------------------------------------
// softmax (4 matrices of 24x24 per b,h) + build fused weights
// Wcat[b][o][j]: rows 0..191 -> out1, 192..383 -> out2; cols 0..191 -> v1, 192..383 -> v2
// ---------------------------------------------------------------------------
__global__ __launch_bounds__(256) void softmax_wcat_kernel(
    const float* __restrict__ G, const float* __restrict__ norms,
    const float* __restrict__ temperature, const float* __restrict__ beta,
    const float* __restrict__ wproj, float* __restrict__ Wcat) {
  const int bh = blockIdx.x;
  const int b = bh >> 3, h = bh & 7;
  __shared__ float sm[4][24][24];  // sa1, ca1, sa2, ca2
  __shared__ float nrm[4][24];     // nq1, nq2, nk1, nk2
  const int tid = threadIdx.x;
  if (tid < 96) {
    int t = tid / 24, ci = tid % 24;
    nrm[t][ci] = fmaxf(norms[(t * NB + b) * NCH + h * 24 + ci], 1e-12f);
  }
  __syncthreads();
  const float T = temperature[h];
  const float sigB = 1.f / (1.f + expf(-beta[0]));
  if (tid < 96) {
    const int m = tid / 24, r = tid % 24;
    const float* Gb = G + (size_t)bh * 2304;
    // m: 0=sa1 (q1 rows, k1 cols, +), 1=ca1 (q1, k2, -), 2=sa2 (q2, k2, +), 3=ca2 (q2, k1, -)
    const int gr = (m >= 2) ? 24 + r : r;
    const int gc0 = (m == 1 || m == 2) ? 24 : 0;
    const float* qn = (m >= 2) ? nrm[1] : nrm[0];
    const float* kn = (m == 1 || m == 2) ? nrm[3] : nrm[2];
    const float sign = (m == 0 || m == 2) ? 1.f : -1.f;
    const float qs = sign * T / qn[r];
    float L[24], mx = -1e30f;
#pragma unroll
    for (int cc = 0; cc < 24; ++cc) {
      L[cc] = Gb[gr * 48 + gc0 + cc] * qs / kn[cc];
      mx = fmaxf(mx, L[cc]);
    }
    float ssum = 0.f;
#pragma unroll
    for (int cc = 0; cc < 24; ++cc) {
      L[cc] = expf(L[cc] - mx);
      ssum += L[cc];
    }
    const float inv = 1.f / ssum;
#pragma unroll
    for (int cc = 0; cc < 24; ++cc) sm[m][r][cc] = L[cc] * inv;
  }
  __syncthreads();
  for (int e = tid; e < 384 * 48; e += 256) {
    const int o = e / 48, dc = e % 48;
    const int part = dc / 24, d = dc % 24;
    const int oc = (o < 192) ? o : o - 192;
    int m;
    float scale;
    if (o < 192) { m = part ? 1 : 0; scale = part ? 1.f : sigB; }
    else         { m = part ? 2 : 3; scale = part ? sigB : 1.f; }
    float s = 0.f;
#pragma unroll
    for (int ci = 0; ci < 24; ++ci) s += wproj[oc * 192 + h * 24 + ci] * sm[m][ci][d];
    Wcat[((size_t)b * 384 + o) * 384 + part * 192 + h * 24 + d] = s * scale;
  }
}

// ---------------------------------------------------------------------------
// final GEMM: out[b][o][n] = sum_j Wcat[b][o][j] * Vcat[b][j][n]
// M=384, K=384 (chunked by 96), N=16384. bf16 V, fp32 out (split into 2 outputs)
// ---------------------------------------------------------------------------
__global__ __launch_bounds__(256) void final_gemm_kernel(
    const u16* __restrict__ qkv1, const u16* __restrict__ qkv2,
    const float* __restrict__ Wcat, float* __restrict__ out) {
  __shared__ float Wt[64][100];
  __shared__ float Xt[96][132];
  const int nbase = blockIdx.x * 128;
  const int obase = blockIdx.y * 64;
  const int b = blockIdx.z;
  const int tid = threadIdx.x;
  const int tx = tid & 15, ty = tid >> 4;

  float4 accL[4], accH[4];
#pragma unroll
  for (int i = 0; i < 4; ++i) {
    accL[i] = make_float4(0.f, 0.f, 0.f, 0.f);
    accH[i] = make_float4(0.f, 0.f, 0.f, 0.f);
  }

  for (int kb = 0; kb < 384; kb += 96) {
    for (int idx = tid; idx < 64 * 24; idx += 256) {
      int r = idx / 24, c4 = (idx % 24) * 4;
      *(float4*)&Wt[r][c4] = *(const float4*)&Wcat[((size_t)b * 384 + obase + r) * 384 + kb + c4];
    }
    for (int idx = tid; idx < 96 * 32; idx += 256) {
      int r = idx >> 5, c4 = (idx & 31) * 4;
      int j = kb + r;
      const u16* p = (j < 192) ? qkv1 + (((size_t)b * NC3 + 384 + j) << 14)
                               : qkv2 + (((size_t)b * NC3 + 384 + j - 192) << 14);
      uint2 v = *(const uint2*)(p + nbase + c4);
      Xt[r][c4 + 0] = bf2f(v.x & 0xffff);
      Xt[r][c4 + 1] = bf2f(v.x >> 16);
      Xt[r][c4 + 2] = bf2f(v.y & 0xffff);
      Xt[r][c4 + 3] = bf2f(v.y >> 16);
    }
    __syncthreads();
    for (int k4 = 0; k4 < 24; ++k4) {
      float4 a0 = *(const float4*)&Wt[ty * 4 + 0][k4 * 4];
      float4 a1 = *(const float4*)&Wt[ty * 4 + 1][k4 * 4];
      float4 a2 = *(const float4*)&Wt[ty * 4 + 2][k4 * 4];
      float4 a3 = *(const float4*)&Wt[ty * 4 + 3][k4 * 4];
#pragma unroll
      for (int kk = 0; kk < 4; ++kk) {
        float4 b0 = *(const float4*)&Xt[k4 * 4 + kk][tx * 8];
        float4 b1 = *(const float4*)&Xt[k4 * 4 + kk][tx * 8 + 4];
        float av0 = SEL4(a0, kk), av1 = SEL4(a1, kk), av2 = SEL4(a2, kk), av3 = SEL4(a3, kk);
        FMA4(accL[0], av0, b0); FMA4(accH[0], av0, b1);
        FMA4(accL[1], av1, b0); FMA4(accH[1], av1, b1);
        FMA4(accL[2], av2, b0); FMA4(accH[2], av2, b1);
        FMA4(accL[3], av3, b0); FMA4(accH[3], av3, b1);
      }
    }
    __syncthreads();
  }
#pragma unroll
  for (int i = 0; i < 4; ++i) {
    const int o = obase + ty * 4 + i;
    float* dst = (o < 192) ? out + (((size_t)b * NCH + o) << 14)
                           : out + 25165824 + (((size_t)b * NCH + o - 192) << 14);
    dst += nbase + tx * 8;
    *(float4*)dst = accL[i];
    *(float4*)(dst + 4) = accH[i];
  }
}

// ---------------------------------------------------------------------------
extern "C" void kernel_launch(void* const* d_in, const int* in_sizes, int n_in,
                              void* d_out, int out_size, void* d_ws, size_t ws_size,
                              hipStream_t stream) {
  (void)in_sizes; (void)n_in; (void)out_size; (void)ws_size;
  const float* x1 = (const float*)d_in[0];
  const float* x2 = (const float*)d_in[1];
  const float* w_qkv1 = (const float*)d_in[2];
  const float* w_dw1 = (const float*)d_in[3];
  const float* w_qkv2 = (const float*)d_in[4];
  const float* w_dw2 = (const float*)d_in[5];
  const float* w_proj = (const float*)d_in[6];
  const float* temperature = (const float*)d_in[7];
  const float* beta = (const float*)d_in[8];
  float* out = (float*)d_out;

  char* wsb = (char*)d_ws;
  u16* pre = (u16*)(wsb);                          // 150,994,944 B
  u16* qkv1 = (u16*)(wsb + 150994944);             // 150,994,944 B
  u16* qkv2 = (u16*)(wsb + 301989888);             // 150,994,944 B
  float* norms = (float*)(wsb + 452984832);        // 24,576 B
  float* G = (float*)(wsb + 453009408);            // 589,824 B
  float* Wcat = (float*)(wsb + 453599232);         // 4,718,592 B
  float* gp = (float*)(wsb + 458317824);           // 9,437,184 B  (total ~446 MB)

  dim3 cgrid(NHW / 128, NC3 / 64, NB);
  const int dwblocks = (int)(((size_t)NB * NC3 * NHW) / 256);

  conv1x1_kernel<<<cgrid, 256, 0, stream>>>(x1, w_qkv1, pre);
  dwconv_kernel<<<dwblocks, 256, 0, stream>>>(pre, w_dw1, qkv1);
  conv1x1_kernel<<<cgrid, 256, 0, stream>>>(x2, w_qkv2, pre);
  dwconv_kernel<<<dwblocks, 256, 0, stream>>>(pre, w_dw2, qkv2);
  norms_kernel<<<4 * NB * NCH, 256, 0, stream>>>(qkv1, qkv2, norms);
  gram_partial_kernel<<<dim3(16, NHEADS, NB), 256, 0, stream>>>(qkv1, qkv2, gp);
  gram_reduce_kernel<<<NB * NHEADS, 256, 0, stream>>>(gp, G);
  softmax_wcat_kernel<<<NB * NHEADS, 256, 0, stream>>>(G, norms, temperature, beta, w_proj, Wcat);
  final_gemm_kernel<<<dim3(NHW / 128, 384 / 64, NB), 256, 0, stream>>>(qkv1, qkv2, Wcat, out);
}

// Round 2
// 1172.874 us; speedup vs baseline: 2.2521x; 2.2521x over previous
//
#include <hip/hip_runtime.h>

typedef unsigned short u16;
typedef unsigned int u32;

#define NB 8
#define NCH 192
#define NC3 576
#define NHW 16384
#define NHEADS 8

typedef __attribute__((ext_vector_type(8))) short s16x8;
typedef __attribute__((ext_vector_type(4))) float f32x4;

__device__ __forceinline__ float bf2f(u32 h) {
  return __uint_as_float(h << 16);
}
__device__ __forceinline__ u16 f2bf(float f) {
  u32 u = __float_as_uint(f);
  u = (u + 0x7fffu + ((u >> 16) & 1u)) >> 16;
  return (u16)u;
}
__device__ __forceinline__ u32 pk2(u16 a, u16 b) { return (u32)a | ((u32)b << 16); }

// XOR swizzle within a 128-byte LDS row: spreads 16-consecutive-row b128 reads
// across 8 distinct 16B slots (2-way aliasing = free), byte-offset domain.
__device__ __forceinline__ int swz(int row) { return ((row >> 1) & 7) << 4; }

__device__ __forceinline__ void gl_lds16(const void* g, void* s) {
  __builtin_amdgcn_global_load_lds((const __attribute__((address_space(1))) unsigned int*)g,
                                   (__attribute__((address_space(3))) unsigned int*)s, 16, 0, 0);
}

// ---------------------------------------------------------------------------
// cast conv weights fp32 -> bf16
// ---------------------------------------------------------------------------
__global__ __launch_bounds__(256) void wcast_kernel(
    const float* __restrict__ w1, const float* __restrict__ w2,
    u16* __restrict__ o1, u16* __restrict__ o2) {
  int i = blockIdx.x * 256 + threadIdx.x;
  if (i < NC3 * NCH) {
    o1[i] = f2bf(w1[i]);
    o2[i] = f2bf(w2[i]);
  }
}

// ---------------------------------------------------------------------------
// conv1x1 MFMA: pre[b][o][n] = sum_k w[o][k] * x[b][k][n]
// M=576 (BM=192), N=16384 (BN=128), K=192 (BK=64). A=w bf16 via global_load_lds
// (pre-swizzled source), B=x fp32 reg-staged transposed into LDS [n][k].
// ---------------------------------------------------------------------------
__global__ __launch_bounds__(256) void conv_mfma_kernel(
    const float* __restrict__ x, const u16* __restrict__ wbf, u16* __restrict__ pre) {
  __shared__ u16 Al[192 * 64];  // [o][k] rows of 128B, swizzled
  __shared__ u16 Bl[128 * 64];  // [n][k] rows of 128B, swizzled
  const int nbase = blockIdx.x * 128;
  const int obase = blockIdx.y * 192;
  const int b = blockIdx.z;
  const int tid = threadIdx.x;
  const int w = tid >> 6, l = tid & 63;
  const int wr = w >> 1, wc = w & 1;

  f32x4 acc[6][4];
#pragma unroll
  for (int m = 0; m < 6; ++m)
#pragma unroll
    for (int nf = 0; nf < 4; ++nf) acc[m][nf] = (f32x4)0.f;

  for (int kb = 0; kb < 192; kb += 64) {
    // A stage: 24KB via global_load_lds, source pre-swizzled
#pragma unroll
    for (int i = 0; i < 6; ++i) {
      const int grp = i * 4 + w;
      const int row = grp * 8 + (l >> 3);
      const int cb = ((l & 7) * 16) ^ swz(row);
      const char* src = (const char*)wbf + (size_t)(obase + row) * 384 + kb * 2 + cb;
      gl_lds16(src, (char*)Al + grp * 1024);
    }
    // B stage: transpose x[k][n] -> Bl[n][k] via 4x4 micro-tiles
#pragma unroll
    for (int pi = 0; pi < 2; ++pi) {
      const int p = pi * 256 + tid;
      const int ng = p & 31, kg = p >> 5;  // ng 0..31 (n/4), kg 0..15 (k/4)
      const float* xr = x + (((size_t)b * NCH + kb + kg * 4) << 14) + nbase + ng * 4;
      float4 f0 = *(const float4*)(xr);
      float4 f1 = *(const float4*)(xr + NHW);
      float4 f2 = *(const float4*)(xr + 2 * NHW);
      float4 f3 = *(const float4*)(xr + 3 * NHW);
      u16 e0[4] = {f2bf(f0.x), f2bf(f0.y), f2bf(f0.z), f2bf(f0.w)};
      u16 e1[4] = {f2bf(f1.x), f2bf(f1.y), f2bf(f1.z), f2bf(f1.w)};
      u16 e2[4] = {f2bf(f2.x), f2bf(f2.y), f2bf(f2.z), f2bf(f2.w)};
      u16 e3[4] = {f2bf(f3.x), f2bf(f3.y), f2bf(f3.z), f2bf(f3.w)};
#pragma unroll
      for (int nn = 0; nn < 4; ++nn) {
        const int row = ng * 4 + nn;
        const int cb = (kg * 8) ^ swz(row);
        *(uint2*)((char*)Bl + row * 128 + cb) = make_uint2(pk2(e0[nn], e1[nn]), pk2(e2[nn], e3[nn]));
      }
    }
    __syncthreads();
#pragma unroll
    for (int kk = 0; kk < 2; ++kk) {
      s16x8 a[6], bv[4];
      const int cbk = kk * 64 + (l >> 4) * 16;
#pragma unroll
      for (int m = 0; m < 6; ++m) {
        const int rowA = wr * 96 + m * 16 + (l & 15);
        a[m] = *(const s16x8*)((const char*)Al + rowA * 128 + (cbk ^ swz(rowA)));
      }
#pragma unroll
      for (int nf = 0; nf < 4; ++nf) {
        const int rowB = wc * 64 + nf * 16 + (l & 15);
        bv[nf] = *(const s16x8*)((const char*)Bl + rowB * 128 + (cbk ^ swz(rowB)));
      }
#pragma unroll
      for (int m = 0; m < 6; ++m)
#pragma unroll
        for (int nf = 0; nf < 4; ++nf)
          acc[m][nf] = __builtin_amdgcn_mfma_f32_16x16x32_bf16(a[m], bv[nf], acc[m][nf], 0, 0, 0);
    }
    __syncthreads();
  }
  // epilogue: D layout col=lane&15, row=(lane>>4)*4+r
#pragma unroll
  for (int m = 0; m < 6; ++m) {
    const int o = obase + wr * 96 + m * 16 + (l >> 4) * 4;
#pragma unroll
    for (int nf = 0; nf < 4; ++nf) {
      const int n = nbase + wc * 64 + nf * 16 + (l & 15);
#pragma unroll
      for (int r = 0; r < 4; ++r)
        pre[(((size_t)b * NC3 + o + r) << 14) + n] = f2bf(acc[m][nf][r]);
    }
  }
}

// ---------------------------------------------------------------------------
// depthwise 3x3, SAME pad. bf16 in/out, fp32 weights.
// ---------------------------------------------------------------------------
__global__ __launch_bounds__(256) void dwconv_kernel(
    const u16* __restrict__ in, const float* __restrict__ wdw, u16* __restrict__ out) {
  size_t gid = (size_t)blockIdx.x * 256 + threadIdx.x;
  const int xx = (int)(gid & 127);
  const int yy = (int)((gid >> 7) & 127);
  const int bc = (int)(gid >> 14);
  const int c = bc % NC3;
  const u16* p = in + ((size_t)bc << 14);
  const float* wc = wdw + c * 9;
  float s = 0.f;
#pragma unroll
  for (int dy = -1; dy <= 1; ++dy) {
    const int y2 = yy + dy;
    if ((unsigned)y2 < 128u) {
      const u16* row = p + (y2 << 7);
#pragma unroll
      for (int dx = -1; dx <= 1; ++dx) {
        const int x2 = xx + dx;
        if ((unsigned)x2 < 128u)
          s = fmaf(wc[(dy + 1) * 3 + (dx + 1)], bf2f(row[x2]), s);
      }
    }
  }
  out[gid] = f2bf(s);
}

// ---------------------------------------------------------------------------
// row L2 norms for q1,q2,k1,k2.  norms[t][b][c]
// ---------------------------------------------------------------------------
__global__ __launch_bounds__(256) void norms_kernel(
    const u16* __restrict__ qkv1, const u16* __restrict__ qkv2, float* __restrict__ norms) {
  const int r = blockIdx.x;
  const int t = r / (NB * NCH);
  const int rem = r % (NB * NCH);
  const int b = rem / NCH, c = rem % NCH;
  const u16* base = (t == 0 || t == 2) ? qkv1 : qkv2;
  const u16* p = base + (((size_t)b * NC3 + (t >= 2 ? 192 : 0) + c) << 14);
  const int tid = threadIdx.x;
  float s = 0.f;
  for (int it = 0; it < 16; ++it) {
    uint2 v = *(const uint2*)(p + (it * 256 + tid) * 4);
    float f0 = bf2f(v.x & 0xffff), f1 = bf2f(v.x >> 16);
    float f2 = bf2f(v.y & 0xffff), f3 = bf2f(v.y >> 16);
    s += f0 * f0 + f1 * f1 + f2 * f2 + f3 * f3;
  }
#pragma unroll
  for (int off = 32; off > 0; off >>= 1) s += __shfl_down(s, off, 64);
  __shared__ float red[4];
  if ((tid & 63) == 0) red[tid >> 6] = s;
  __syncthreads();
  if (tid == 0) norms[r] = sqrtf(red[0] + red[1] + red[2] + red[3]);
}

// ---------------------------------------------------------------------------
// Gram via MFMA, fragments direct from global (NT: contraction over n).
// rows=[q1;q2](48) x cols=[k1;k2](48), partials per 1024-n chunk.
// ---------------------------------------------------------------------------
__global__ __launch_bounds__(256) void gram_mfma_kernel(
    const u16* __restrict__ qkv1, const u16* __restrict__ qkv2, float* __restrict__ gp) {
  const int nc = blockIdx.x, h = blockIdx.y, b = blockIdx.z;
  const int tid = threadIdx.x;
  const int w = tid >> 6, l = tid & 63;

  const u16* qp[3];
  const u16* kp[3];
#pragma unroll
  for (int m = 0; m < 3; ++m) {
    const int rq = m * 16 + (l & 15);
    const int cc = h * 24 + (rq < 24 ? rq : rq - 24);
    const u16* basep = (rq < 24) ? qkv1 : qkv2;
    qp[m] = basep + (((size_t)b * NC3 + cc) << 14);
    kp[m] = basep + (((size_t)b * NC3 + 192 + cc) << 14);
  }
  const int kbase = nc * 1024 + w * 256 + (l >> 4) * 8;

  f32x4 acc[3][3];
#pragma unroll
  for (int m = 0; m < 3; ++m)
#pragma unroll
    for (int nf = 0; nf < 3; ++nf) acc[m][nf] = (f32x4)0.f;

  for (int t = 0; t < 8; ++t) {
    const int ko = kbase + t * 32;
    s16x8 a[3], bv[3];
#pragma unroll
    for (int m = 0; m < 3; ++m) {
      a[m] = *(const s16x8*)(qp[m] + ko);
      bv[m] = *(const s16x8*)(kp[m] + ko);
    }
#pragma unroll
    for (int m = 0; m < 3; ++m)
#pragma unroll
      for (int nf = 0; nf < 3; ++nf)
        acc[m][nf] = __builtin_amdgcn_mfma_f32_16x16x32_bf16(a[m], bv[nf], acc[m][nf], 0, 0, 0);
  }

  __shared__ float red[4][48][48];
#pragma unroll
  for (int m = 0; m < 3; ++m)
#pragma unroll
    for (int nf = 0; nf < 3; ++nf)
#pragma unroll
      for (int r = 0; r < 4; ++r)
        red[w][m * 16 + (l >> 4) * 4 + r][nf * 16 + (l & 15)] = acc[m][nf][r];
  __syncthreads();
  float* dst = gp + ((((size_t)b * 8 + h) * 16 + nc) * 2304);
  for (int e = tid; e < 2304; e += 256) {
    const int rr = e / 48, cc = e % 48;
    dst[e] = red[0][rr][cc] + red[1][rr][cc] + red[2][rr][cc] + red[3][rr][cc];
  }
}

__global__ __launch_bounds__(256) void gram_reduce_kernel(
    const float* __restrict__ gp, float* __restrict__ G) {
  const int bh = blockIdx.x;
  for (int e = threadIdx.x; e < 2304; e += 256) {
    float s = 0.f;
    for (int p = 0; p < 16; ++p) s += gp[((size_t)bh * 16 + p) * 2304 + e];
    G[(size_t)bh * 2304 + e] = s;
  }
}

// ---------------------------------------------------------------------------
// softmax (4x 24x24 per b,h) + fused weights, bf16 output
// ---------------------------------------------------------------------------
__global__ __launch_bounds__(256) void softmax_wcat_kernel(
    const float* __restrict__ G, const float* __restrict__ norms,
    const float* __restrict__ temperature, const float* __restrict__ beta,
    const float* __restrict__ wproj, u16* __restrict__ Wcat) {
  const int bh = blockIdx.x;
  const int b = bh >> 3, h = bh & 7;
  __shared__ float sm[4][24][24];
  __shared__ float nrm[4][24];
  const int tid = threadIdx.x;
  if (tid < 96) {
    int t = tid / 24, ci = tid % 24;
    nrm[t][ci] = fmaxf(norms[(t * NB + b) * NCH + h * 24 + ci], 1e-12f);
  }
  __syncthreads();
  const float T = temperature[h];
  const float sigB = 1.f / (1.f + expf(-beta[0]));
  if (tid < 96) {
    const int m = tid / 24, r = tid % 24;
    const float* Gb = G + (size_t)bh * 2304;
    const int gr = (m >= 2) ? 24 + r : r;
    const int gc0 = (m == 1 || m == 2) ? 24 : 0;
    const float* qn = (m >= 2) ? nrm[1] : nrm[0];
    const float* kn = (m == 1 || m == 2) ? nrm[3] : nrm[2];
    const float sign = (m == 0 || m == 2) ? 1.f : -1.f;
    const float qs = sign * T / qn[r];
    float L[24], mx = -1e30f;
#pragma unroll
    for (int cc = 0; cc < 24; ++cc) {
      L[cc] = Gb[gr * 48 + gc0 + cc] * qs / kn[cc];
      mx = fmaxf(mx, L[cc]);
    }
    float ssum = 0.f;
#pragma unroll
    for (int cc = 0; cc < 24; ++cc) {
      L[cc] = expf(L[cc] - mx);
      ssum += L[cc];
    }
    const float inv = 1.f / ssum;
#pragma unroll
    for (int cc = 0; cc < 24; ++cc) sm[m][r][cc] = L[cc] * inv;
  }
  __syncthreads();
  for (int e = tid; e < 384 * 48; e += 256) {
    const int o = e / 48, dc = e % 48;
    const int part = dc / 24, d = dc % 24;
    const int oc = (o < 192) ? o : o - 192;
    int m;
    float scale;
    if (o < 192) { m = part ? 1 : 0; scale = part ? 1.f : sigB; }
    else         { m = part ? 2 : 3; scale = part ? sigB : 1.f; }
    float s = 0.f;
#pragma unroll
    for (int ci = 0; ci < 24; ++ci) s += wproj[oc * 192 + h * 24 + ci] * sm[m][ci][d];
    Wcat[((size_t)b * 384 + o) * 384 + part * 192 + h * 24 + d] = f2bf(s * scale);
  }
}

// ---------------------------------------------------------------------------
// final GEMM MFMA: out[b][o][n] = sum_j Wcat[b][o][j] * V[j][n]
// M=384 (BM=128), N=16384 (BN=128), K=384 (BK=64). A via global_load_lds,
// B reg-staged transposed from v planes.
// ---------------------------------------------------------------------------
__global__ __launch_bounds__(256) void final_mfma_kernel(
    const u16* __restrict__ qkv1, const u16* __restrict__ qkv2,
    const u16* __restrict__ Wcat, float* __restrict__ out) {
  __shared__ u16 Al[128 * 64];
  __shared__ u16 Bl[128 * 64];
  const int nbase = blockIdx.x * 128;
  const int obase = blockIdx.y * 128;
  const int b = blockIdx.z;
  const int tid = threadIdx.x;
  const int w = tid >> 6, l = tid & 63;
  const int wr = w >> 1, wc = w & 1;

  f32x4 acc[4][4];
#pragma unroll
  for (int m = 0; m < 4; ++m)
#pragma unroll
    for (int nf = 0; nf < 4; ++nf) acc[m][nf] = (f32x4)0.f;

  for (int kb = 0; kb < 384; kb += 64) {
#pragma unroll
    for (int i = 0; i < 4; ++i) {
      const int grp = i * 4 + w;
      const int row = grp * 8 + (l >> 3);
      const int cb = ((l & 7) * 16) ^ swz(row);
      const char* src = (const char*)Wcat + ((size_t)b * 384 + obase + row) * 768 + kb * 2 + cb;
      gl_lds16(src, (char*)Al + grp * 1024);
    }
    const u16* vbase = (kb < 192) ? qkv1 + (((size_t)b * NC3 + 384 + kb) << 14)
                                  : qkv2 + (((size_t)b * NC3 + 384 + kb - 192) << 14);
#pragma unroll
    for (int pi = 0; pi < 2; ++pi) {
      const int p = pi * 256 + tid;
      const int ng = p & 31, kg = p >> 5;
      const u16* vr = vbase + (((size_t)kg * 4) << 14) + nbase + ng * 4;
      uint2 r0 = *(const uint2*)(vr);
      uint2 r1 = *(const uint2*)(vr + NHW);
      uint2 r2 = *(const uint2*)(vr + 2 * NHW);
      uint2 r3 = *(const uint2*)(vr + 3 * NHW);
      u16 e0[4] = {(u16)(r0.x & 0xffff), (u16)(r0.x >> 16), (u16)(r0.y & 0xffff), (u16)(r0.y >> 16)};
      u16 e1[4] = {(u16)(r1.x & 0xffff), (u16)(r1.x >> 16), (u16)(r1.y & 0xffff), (u16)(r1.y >> 16)};
      u16 e2[4] = {(u16)(r2.x & 0xffff), (u16)(r2.x >> 16), (u16)(r2.y & 0xffff), (u16)(r2.y >> 16)};
      u16 e3[4] = {(u16)(r3.x & 0xffff), (u16)(r3.x >> 16), (u16)(r3.y & 0xffff), (u16)(r3.y >> 16)};
#pragma unroll
      for (int nn = 0; nn < 4; ++nn) {
        const int row = ng * 4 + nn;
        const int cb = (kg * 8) ^ swz(row);
        *(uint2*)((char*)Bl + row * 128 + cb) = make_uint2(pk2(e0[nn], e1[nn]), pk2(e2[nn], e3[nn]));
      }
    }
    __syncthreads();
#pragma unroll
    for (int kk = 0; kk < 2; ++kk) {
      s16x8 a[4], bv[4];
      const int cbk = kk * 64 + (l >> 4) * 16;
#pragma unroll
      for (int m = 0; m < 4; ++m) {
        const int rowA = wr * 64 + m * 16 + (l & 15);
        a[m] = *(const s16x8*)((const char*)Al + rowA * 128 + (cbk ^ swz(rowA)));
      }
#pragma unroll
      for (int nf = 0; nf < 4; ++nf) {
        const int rowB = wc * 64 + nf * 16 + (l & 15);
        bv[nf] = *(const s16x8*)((const char*)Bl + rowB * 128 + (cbk ^ swz(rowB)));
      }
#pragma unroll
      for (int m = 0; m < 4; ++m)
#pragma unroll
        for (int nf = 0; nf < 4; ++nf)
          acc[m][nf] = __builtin_amdgcn_mfma_f32_16x16x32_bf16(a[m], bv[nf], acc[m][nf], 0, 0, 0);
    }
    __syncthreads();
  }
#pragma unroll
  for (int m = 0; m < 4; ++m) {
    const int o = obase + wr * 64 + m * 16 + (l >> 4) * 4;
#pragma unroll
    for (int nf = 0; nf < 4; ++nf) {
      const int n = nbase + wc * 64 + nf * 16 + (l & 15);
#pragma unroll
      for (int r = 0; r < 4; ++r) {
        const int oo = o + r;
        float* dst = (oo < 192) ? out + (((size_t)b * NCH + oo) << 14) + n
                                : out + 25165824 + (((size_t)b * NCH + oo - 192) << 14) + n;
        *dst = acc[m][nf][r];
      }
    }
  }
}

// ---------------------------------------------------------------------------
extern "C" void kernel_launch(void* const* d_in, const int* in_sizes, int n_in,
                              void* d_out, int out_size, void* d_ws, size_t ws_size,
                              hipStream_t stream) {
  (void)in_sizes; (void)n_in; (void)out_size; (void)ws_size;
  const float* x1 = (const float*)d_in[0];
  const float* x2 = (const float*)d_in[1];
  const float* w_qkv1 = (const float*)d_in[2];
  const float* w_dw1 = (const float*)d_in[3];
  const float* w_qkv2 = (const float*)d_in[4];
  const float* w_dw2 = (const float*)d_in[5];
  const float* w_proj = (const float*)d_in[6];
  const float* temperature = (const float*)d_in[7];
  const float* beta = (const float*)d_in[8];
  float* out = (float*)d_out;

  char* wsb = (char*)d_ws;
  u16* pre = (u16*)(wsb);                       // 150,994,944
  u16* qkv1 = (u16*)(wsb + 150994944);          // 150,994,944
  u16* qkv2 = (u16*)(wsb + 301989888);          // 150,994,944
  u16* wbf1 = (u16*)(wsb + 452984832);          // 221,184
  u16* wbf2 = (u16*)(wsb + 453206016);          // 221,184
  float* norms = (float*)(wsb + 453427200);     // 24,576
  float* G = (float*)(wsb + 453451776);         // 589,824
  u16* WcatBf = (u16*)(wsb + 454041600);        // 2,359,296
  float* gp = (float*)(wsb + 456400896);        // 9,437,184  -> end 465,838,080

  const int dwblocks = (int)(((size_t)NB * NC3 * NHW) / 256);

  wcast_kernel<<<(NC3 * NCH + 255) / 256, 256, 0, stream>>>(w_qkv1, w_qkv2, wbf1, wbf2);
  conv_mfma_kernel<<<dim3(128, 3, NB), 256, 0, stream>>>(x1, wbf1, pre);
  dwconv_kernel<<<dwblocks, 256, 0, stream>>>(pre, w_dw1, qkv1);
  conv_mfma_kernel<<<dim3(128, 3, NB), 256, 0, stream>>>(x2, wbf2, pre);
  dwconv_kernel<<<dwblocks, 256, 0, stream>>>(pre, w_dw2, qkv2);
  norms_kernel<<<4 * NB * NCH, 256, 0, stream>>>(qkv1, qkv2, norms);
  gram_mfma_kernel<<<dim3(16, NHEADS, NB), 256, 0, stream>>>(qkv1, qkv2, gp);
  gram_reduce_kernel<<<NB * NHEADS, 256, 0, stream>>>(gp, G);
  softmax_wcat_kernel<<<NB * NHEADS, 256, 0, stream>>>(G, norms, temperature, beta, w_proj, WcatBf);
  final_mfma_kernel<<<dim3(128, 3, NB), 256, 0, stream>>>(qkv1, qkv2, WcatBf, out);
}

// Round 3
// 574.041 us; speedup vs baseline: 4.6014x; 2.0432x over previous
//
#include <hip/hip_runtime.h>

typedef unsigned short u16;
typedef unsigned int u32;

#define NB 8
#define NCH 192
#define NC3 576
#define NHW 16384
#define NHEADS 8

typedef __attribute__((ext_vector_type(8))) short s16x8;
typedef __attribute__((ext_vector_type(4))) float f32x4;

__device__ __forceinline__ float bf2f(u32 h) {
  return __uint_as_float(h << 16);
}
__device__ __forceinline__ u16 f2bf(float f) {
  u32 u = __float_as_uint(f);
  u = (u + 0x7fffu + ((u >> 16) & 1u)) >> 16;
  return (u16)u;
}
__device__ __forceinline__ u32 pk2(u16 a, u16 b) { return (u32)a | ((u32)b << 16); }

// XOR swizzle within a 128-byte LDS row: spreads 16-consecutive-row b128 reads
// across 8 distinct 16B slots (2-way aliasing = free), byte-offset domain.
__device__ __forceinline__ int swz(int row) { return ((row >> 1) & 7) << 4; }

__device__ __forceinline__ void gl_lds16(const void* g, void* s) {
  __builtin_amdgcn_global_load_lds((const __attribute__((address_space(1))) unsigned int*)g,
                                   (__attribute__((address_space(3))) unsigned int*)s, 16, 0, 0);
}

// ---------------------------------------------------------------------------
// cast conv weights fp32 -> bf16
// ---------------------------------------------------------------------------
__global__ __launch_bounds__(256) void wcast_kernel(
    const float* __restrict__ w1, const float* __restrict__ w2,
    u16* __restrict__ o1, u16* __restrict__ o2) {
  int i = blockIdx.x * 256 + threadIdx.x;
  if (i < NC3 * NCH) {
    o1[i] = f2bf(w1[i]);
    o2[i] = f2bf(w2[i]);
  }
}

// ---------------------------------------------------------------------------
// conv1x1 MFMA: pre[b][o][n] = sum_k w[o][k] * x[b][k][n]
// ---------------------------------------------------------------------------
__global__ __launch_bounds__(256) void conv_mfma_kernel(
    const float* __restrict__ x, const u16* __restrict__ wbf, u16* __restrict__ pre) {
  __shared__ u16 Al[192 * 64];  // [o][k] rows of 128B, swizzled
  __shared__ u16 Bl[128 * 64];  // [n][k] rows of 128B, swizzled
  const int nbase = blockIdx.x * 128;
  const int obase = blockIdx.y * 192;
  const int b = blockIdx.z;
  const int tid = threadIdx.x;
  const int w = tid >> 6, l = tid & 63;
  const int wr = w >> 1, wc = w & 1;

  f32x4 acc[6][4];
#pragma unroll
  for (int m = 0; m < 6; ++m)
#pragma unroll
    for (int nf = 0; nf < 4; ++nf) acc[m][nf] = (f32x4)0.f;

  for (int kb = 0; kb < 192; kb += 64) {
#pragma unroll
    for (int i = 0; i < 6; ++i) {
      const int grp = i * 4 + w;
      const int row = grp * 8 + (l >> 3);
      const int cb = ((l & 7) * 16) ^ swz(row);
      const char* src = (const char*)wbf + (size_t)(obase + row) * 384 + kb * 2 + cb;
      gl_lds16(src, (char*)Al + grp * 1024);
    }
#pragma unroll
    for (int pi = 0; pi < 2; ++pi) {
      const int p = pi * 256 + tid;
      const int ng = p & 31, kg = p >> 5;
      const float* xr = x + (((size_t)b * NCH + kb + kg * 4) << 14) + nbase + ng * 4;
      float4 f0 = *(const float4*)(xr);
      float4 f1 = *(const float4*)(xr + NHW);
      float4 f2 = *(const float4*)(xr + 2 * NHW);
      float4 f3 = *(const float4*)(xr + 3 * NHW);
      u16 e0[4] = {f2bf(f0.x), f2bf(f0.y), f2bf(f0.z), f2bf(f0.w)};
      u16 e1[4] = {f2bf(f1.x), f2bf(f1.y), f2bf(f1.z), f2bf(f1.w)};
      u16 e2[4] = {f2bf(f2.x), f2bf(f2.y), f2bf(f2.z), f2bf(f2.w)};
      u16 e3[4] = {f2bf(f3.x), f2bf(f3.y), f2bf(f3.z), f2bf(f3.w)};
#pragma unroll
      for (int nn = 0; nn < 4; ++nn) {
        const int row = ng * 4 + nn;
        const int cb = (kg * 8) ^ swz(row);
        *(uint2*)((char*)Bl + row * 128 + cb) = make_uint2(pk2(e0[nn], e1[nn]), pk2(e2[nn], e3[nn]));
      }
    }
    __syncthreads();
#pragma unroll
    for (int kk = 0; kk < 2; ++kk) {
      s16x8 a[6], bv[4];
      const int cbk = kk * 64 + (l >> 4) * 16;
#pragma unroll
      for (int m = 0; m < 6; ++m) {
        const int rowA = wr * 96 + m * 16 + (l & 15);
        a[m] = *(const s16x8*)((const char*)Al + rowA * 128 + (cbk ^ swz(rowA)));
      }
#pragma unroll
      for (int nf = 0; nf < 4; ++nf) {
        const int rowB = wc * 64 + nf * 16 + (l & 15);
        bv[nf] = *(const s16x8*)((const char*)Bl + rowB * 128 + (cbk ^ swz(rowB)));
      }
#pragma unroll
      for (int m = 0; m < 6; ++m)
#pragma unroll
        for (int nf = 0; nf < 4; ++nf)
          acc[m][nf] = __builtin_amdgcn_mfma_f32_16x16x32_bf16(a[m], bv[nf], acc[m][nf], 0, 0, 0);
    }
    __syncthreads();
  }
#pragma unroll
  for (int m = 0; m < 6; ++m) {
    const int o = obase + wr * 96 + m * 16 + (l >> 4) * 4;
#pragma unroll
    for (int nf = 0; nf < 4; ++nf) {
      const int n = nbase + wc * 64 + nf * 16 + (l & 15);
#pragma unroll
      for (int r = 0; r < 4; ++r)
        pre[(((size_t)b * NC3 + o + r) << 14) + n] = f2bf(acc[m][nf][r]);
    }
  }
}

// ---------------------------------------------------------------------------
// depthwise 3x3, SAME pad, vectorized: 8 px per thread along x.
// per row: one 16B vector load + 2 scalar edge loads.
// ---------------------------------------------------------------------------
__global__ __launch_bounds__(256) void dwconv_kernel(
    const u16* __restrict__ in, const float* __restrict__ wdw, u16* __restrict__ out) {
  const size_t t = (size_t)blockIdx.x * 256 + threadIdx.x;
  const int xc = (int)(t & 15);          // 8-px chunk within row
  const int yy = (int)((t >> 4) & 127);
  const int bc = (int)(t >> 11);
  const int c = bc % NC3;
  const u16* p = in + ((size_t)bc << 14);
  const float* wc = wdw + c * 9;
  const int x0 = xc * 8;

  float a[3][10];
#pragma unroll
  for (int r = 0; r < 3; ++r) {
    const int y2 = yy + r - 1;
    if ((unsigned)y2 < 128u) {
      const u16* row = p + (y2 << 7);
      uint4 v = *(const uint4*)(row + x0);
      a[r][1] = bf2f(v.x & 0xffff); a[r][2] = bf2f(v.x >> 16);
      a[r][3] = bf2f(v.y & 0xffff); a[r][4] = bf2f(v.y >> 16);
      a[r][5] = bf2f(v.z & 0xffff); a[r][6] = bf2f(v.z >> 16);
      a[r][7] = bf2f(v.w & 0xffff); a[r][8] = bf2f(v.w >> 16);
      a[r][0] = (x0 > 0) ? bf2f(row[x0 - 1]) : 0.f;
      a[r][9] = (x0 + 8 < 128) ? bf2f(row[x0 + 8]) : 0.f;
    } else {
#pragma unroll
      for (int j = 0; j < 10; ++j) a[r][j] = 0.f;
    }
  }
  const float w00 = wc[0], w01 = wc[1], w02 = wc[2];
  const float w10 = wc[3], w11 = wc[4], w12 = wc[5];
  const float w20 = wc[6], w21 = wc[7], w22 = wc[8];
  u16 o[8];
#pragma unroll
  for (int j = 0; j < 8; ++j) {
    float s = a[0][j] * w00;
    s = fmaf(a[0][j + 1], w01, s);
    s = fmaf(a[0][j + 2], w02, s);
    s = fmaf(a[1][j], w10, s);
    s = fmaf(a[1][j + 1], w11, s);
    s = fmaf(a[1][j + 2], w12, s);
    s = fmaf(a[2][j], w20, s);
    s = fmaf(a[2][j + 1], w21, s);
    s = fmaf(a[2][j + 2], w22, s);
    o[j] = f2bf(s);
  }
  *(uint4*)(out + (t << 3)) =
      make_uint4(pk2(o[0], o[1]), pk2(o[2], o[3]), pk2(o[4], o[5]), pk2(o[6], o[7]));
}

// ---------------------------------------------------------------------------
// row L2 norms for q1,q2,k1,k2.  norms[t][b][c]
// ---------------------------------------------------------------------------
__global__ __launch_bounds__(256) void norms_kernel(
    const u16* __restrict__ qkv1, const u16* __restrict__ qkv2, float* __restrict__ norms) {
  const int r = blockIdx.x;
  const int t = r / (NB * NCH);
  const int rem = r % (NB * NCH);
  const int b = rem / NCH, c = rem % NCH;
  const u16* base = (t == 0 || t == 2) ? qkv1 : qkv2;
  const u16* p = base + (((size_t)b * NC3 + (t >= 2 ? 192 : 0) + c) << 14);
  const int tid = threadIdx.x;
  float s = 0.f;
  for (int it = 0; it < 8; ++it) {
    uint4 v = *(const uint4*)(p + (it * 256 + tid) * 8);
    float f0 = bf2f(v.x & 0xffff), f1 = bf2f(v.x >> 16);
    float f2 = bf2f(v.y & 0xffff), f3 = bf2f(v.y >> 16);
    float f4 = bf2f(v.z & 0xffff), f5 = bf2f(v.z >> 16);
    float f6 = bf2f(v.w & 0xffff), f7 = bf2f(v.w >> 16);
    s += f0 * f0 + f1 * f1 + f2 * f2 + f3 * f3 + f4 * f4 + f5 * f5 + f6 * f6 + f7 * f7;
  }
#pragma unroll
  for (int off = 32; off > 0; off >>= 1) s += __shfl_down(s, off, 64);
  __shared__ float red[4];
  if ((tid & 63) == 0) red[tid >> 6] = s;
  __syncthreads();
  if (tid == 0) norms[r] = sqrtf(red[0] + red[1] + red[2] + red[3]);
}

// ---------------------------------------------------------------------------
// Gram via MFMA, fragments direct from global (NT: contraction over n).
// ---------------------------------------------------------------------------
__global__ __launch_bounds__(256) void gram_mfma_kernel(
    const u16* __restrict__ qkv1, const u16* __restrict__ qkv2, float* __restrict__ gp) {
  const int nc = blockIdx.x, h = blockIdx.y, b = blockIdx.z;
  const int tid = threadIdx.x;
  const int w = tid >> 6, l = tid & 63;

  const u16* qp[3];
  const u16* kp[3];
#pragma unroll
  for (int m = 0; m < 3; ++m) {
    const int rq = m * 16 + (l & 15);
    const int cc = h * 24 + (rq < 24 ? rq : rq - 24);
    const u16* basep = (rq < 24) ? qkv1 : qkv2;
    qp[m] = basep + (((size_t)b * NC3 + cc) << 14);
    kp[m] = basep + (((size_t)b * NC3 + 192 + cc) << 14);
  }
  const int kbase = nc * 1024 + w * 256 + (l >> 4) * 8;

  f32x4 acc[3][3];
#pragma unroll
  for (int m = 0; m < 3; ++m)
#pragma unroll
    for (int nf = 0; nf < 3; ++nf) acc[m][nf] = (f32x4)0.f;

  for (int t = 0; t < 8; ++t) {
    const int ko = kbase + t * 32;
    s16x8 a[3], bv[3];
#pragma unroll
    for (int m = 0; m < 3; ++m) {
      a[m] = *(const s16x8*)(qp[m] + ko);
      bv[m] = *(const s16x8*)(kp[m] + ko);
    }
#pragma unroll
    for (int m = 0; m < 3; ++m)
#pragma unroll
      for (int nf = 0; nf < 3; ++nf)
        acc[m][nf] = __builtin_amdgcn_mfma_f32_16x16x32_bf16(a[m], bv[nf], acc[m][nf], 0, 0, 0);
  }

  __shared__ float red[4][48][48];
#pragma unroll
  for (int m = 0; m < 3; ++m)
#pragma unroll
    for (int nf = 0; nf < 3; ++nf)
#pragma unroll
      for (int r = 0; r < 4; ++r)
        red[w][m * 16 + (l >> 4) * 4 + r][nf * 16 + (l & 15)] = acc[m][nf][r];
  __syncthreads();
  float* dst = gp + ((((size_t)b * 8 + h) * 16 + nc) * 2304);
  for (int e = tid; e < 2304; e += 256) {
    const int rr = e / 48, cc = e % 48;
    dst[e] = red[0][rr][cc] + red[1][rr][cc] + red[2][rr][cc] + red[3][rr][cc];
  }
}

__global__ __launch_bounds__(256) void gram_reduce_kernel(
    const float* __restrict__ gp, float* __restrict__ G) {
  const int bh = blockIdx.x;
  for (int e = threadIdx.x; e < 2304; e += 256) {
    float s = 0.f;
    for (int p = 0; p < 16; ++p) s += gp[((size_t)bh * 16 + p) * 2304 + e];
    G[(size_t)bh * 2304 + e] = s;
  }
}

// ---------------------------------------------------------------------------
// softmax (4x 24x24 per b,h) + fused weights, bf16 output
// ---------------------------------------------------------------------------
__global__ __launch_bounds__(256) void softmax_wcat_kernel(
    const float* __restrict__ G, const float* __restrict__ norms,
    const float* __restrict__ temperature, const float* __restrict__ beta,
    const float* __restrict__ wproj, u16* __restrict__ Wcat) {
  const int bh = blockIdx.x;
  const int b = bh >> 3, h = bh & 7;
  __shared__ float sm[4][24][24];
  __shared__ float nrm[4][24];
  const int tid = threadIdx.x;
  if (tid < 96) {
    int t = tid / 24, ci = tid % 24;
    nrm[t][ci] = fmaxf(norms[(t * NB + b) * NCH + h * 24 + ci], 1e-12f);
  }
  __syncthreads();
  const float T = temperature[h];
  const float sigB = 1.f / (1.f + expf(-beta[0]));
  if (tid < 96) {
    const int m = tid / 24, r = tid % 24;
    const float* Gb = G + (size_t)bh * 2304;
    const int gr = (m >= 2) ? 24 + r : r;
    const int gc0 = (m == 1 || m == 2) ? 24 : 0;
    const float* qn = (m >= 2) ? nrm[1] : nrm[0];
    const float* kn = (m == 1 || m == 2) ? nrm[3] : nrm[2];
    const float sign = (m == 0 || m == 2) ? 1.f : -1.f;
    const float qs = sign * T / qn[r];
    float L[24], mx = -1e30f;
#pragma unroll
    for (int cc = 0; cc < 24; ++cc) {
      L[cc] = Gb[gr * 48 + gc0 + cc] * qs / kn[cc];
      mx = fmaxf(mx, L[cc]);
    }
    float ssum = 0.f;
#pragma unroll
    for (int cc = 0; cc < 24; ++cc) {
      L[cc] = expf(L[cc] - mx);
      ssum += L[cc];
    }
    const float inv = 1.f / ssum;
#pragma unroll
    for (int cc = 0; cc < 24; ++cc) sm[m][r][cc] = L[cc] * inv;
  }
  __syncthreads();
  for (int e = tid; e < 384 * 48; e += 256) {
    const int o = e / 48, dc = e % 48;
    const int part = dc / 24, d = dc % 24;
    const int oc = (o < 192) ? o : o - 192;
    int m;
    float scale;
    if (o < 192) { m = part ? 1 : 0; scale = part ? 1.f : sigB; }
    else         { m = part ? 2 : 3; scale = part ? sigB : 1.f; }
    float s = 0.f;
#pragma unroll
    for (int ci = 0; ci < 24; ++ci) s += wproj[oc * 192 + h * 24 + ci] * sm[m][ci][d];
    Wcat[((size_t)b * 384 + o) * 384 + part * 192 + h * 24 + d] = f2bf(s * scale);
  }
}

// ---------------------------------------------------------------------------
// final GEMM MFMA: out[b][o][n] = sum_j Wcat[b][o][j] * V[j][n]
// ---------------------------------------------------------------------------
__global__ __launch_bounds__(256) void final_mfma_kernel(
    const u16* __restrict__ qkv1, const u16* __restrict__ qkv2,
    const u16* __restrict__ Wcat, float* __restrict__ out) {
  __shared__ u16 Al[128 * 64];
  __shared__ u16 Bl[128 * 64];
  const int nbase = blockIdx.x * 128;
  const int obase = blockIdx.y * 128;
  const int b = blockIdx.z;
  const int tid = threadIdx.x;
  const int w = tid >> 6, l = tid & 63;
  const int wr = w >> 1, wc = w & 1;

  f32x4 acc[4][4];
#pragma unroll
  for (int m = 0; m < 4; ++m)
#pragma unroll
    for (int nf = 0; nf < 4; ++nf) acc[m][nf] = (f32x4)0.f;

  for (int kb = 0; kb < 384; kb += 64) {
#pragma unroll
    for (int i = 0; i < 4; ++i) {
      const int grp = i * 4 + w;
      const int row = grp * 8 + (l >> 3);
      const int cb = ((l & 7) * 16) ^ swz(row);
      const char* src = (const char*)Wcat + ((size_t)b * 384 + obase + row) * 768 + kb * 2 + cb;
      gl_lds16(src, (char*)Al + grp * 1024);
    }
    const u16* vbase = (kb < 192) ? qkv1 + (((size_t)b * NC3 + 384 + kb) << 14)
                                  : qkv2 + (((size_t)b * NC3 + 384 + kb - 192) << 14);
#pragma unroll
    for (int pi = 0; pi < 2; ++pi) {
      const int p = pi * 256 + tid;
      const int ng = p & 31, kg = p >> 5;
      const u16* vr = vbase + (((size_t)kg * 4) << 14) + nbase + ng * 4;
      uint2 r0 = *(const uint2*)(vr);
      uint2 r1 = *(const uint2*)(vr + NHW);
      uint2 r2 = *(const uint2*)(vr + 2 * NHW);
      uint2 r3 = *(const uint2*)(vr + 3 * NHW);
      u16 e0[4] = {(u16)(r0.x & 0xffff), (u16)(r0.x >> 16), (u16)(r0.y & 0xffff), (u16)(r0.y >> 16)};
      u16 e1[4] = {(u16)(r1.x & 0xffff), (u16)(r1.x >> 16), (u16)(r1.y & 0xffff), (u16)(r1.y >> 16)};
      u16 e2[4] = {(u16)(r2.x & 0xffff), (u16)(r2.x >> 16), (u16)(r2.y & 0xffff), (u16)(r2.y >> 16)};
      u16 e3[4] = {(u16)(r3.x & 0xffff), (u16)(r3.x >> 16), (u16)(r3.y & 0xffff), (u16)(r3.y >> 16)};
#pragma unroll
      for (int nn = 0; nn < 4; ++nn) {
        const int row = ng * 4 + nn;
        const int cb = (kg * 8) ^ swz(row);
        *(uint2*)((char*)Bl + row * 128 + cb) = make_uint2(pk2(e0[nn], e1[nn]), pk2(e2[nn], e3[nn]));
      }
    }
    __syncthreads();
#pragma unroll
    for (int kk = 0; kk < 2; ++kk) {
      s16x8 a[4], bv[4];
      const int cbk = kk * 64 + (l >> 4) * 16;
#pragma unroll
      for (int m = 0; m < 4; ++m) {
        const int rowA = wr * 64 + m * 16 + (l & 15);
        a[m] = *(const s16x8*)((const char*)Al + rowA * 128 + (cbk ^ swz(rowA)));
      }
#pragma unroll
      for (int nf = 0; nf < 4; ++nf) {
        const int rowB = wc * 64 + nf * 16 + (l & 15);
        bv[nf] = *(const s16x8*)((const char*)Bl + rowB * 128 + (cbk ^ swz(rowB)));
      }
#pragma unroll
      for (int m = 0; m < 4; ++m)
#pragma unroll
        for (int nf = 0; nf < 4; ++nf)
          acc[m][nf] = __builtin_amdgcn_mfma_f32_16x16x32_bf16(a[m], bv[nf], acc[m][nf], 0, 0, 0);
    }
    __syncthreads();
  }
#pragma unroll
  for (int m = 0; m < 4; ++m) {
    const int o = obase + wr * 64 + m * 16 + (l >> 4) * 4;
#pragma unroll
    for (int nf = 0; nf < 4; ++nf) {
      const int n = nbase + wc * 64 + nf * 16 + (l & 15);
#pragma unroll
      for (int r = 0; r < 4; ++r) {
        const int oo = o + r;
        float* dst = (oo < 192) ? out + (((size_t)b * NCH + oo) << 14) + n
                                : out + 25165824 + (((size_t)b * NCH + oo - 192) << 14) + n;
        *dst = acc[m][nf][r];
      }
    }
  }
}

// ---------------------------------------------------------------------------
extern "C" void kernel_launch(void* const* d_in, const int* in_sizes, int n_in,
                              void* d_out, int out_size, void* d_ws, size_t ws_size,
                              hipStream_t stream) {
  (void)in_sizes; (void)n_in; (void)out_size; (void)ws_size;
  const float* x1 = (const float*)d_in[0];
  const float* x2 = (const float*)d_in[1];
  const float* w_qkv1 = (const float*)d_in[2];
  const float* w_dw1 = (const float*)d_in[3];
  const float* w_qkv2 = (const float*)d_in[4];
  const float* w_dw2 = (const float*)d_in[5];
  const float* w_proj = (const float*)d_in[6];
  const float* temperature = (const float*)d_in[7];
  const float* beta = (const float*)d_in[8];
  float* out = (float*)d_out;

  char* wsb = (char*)d_ws;
  u16* pre = (u16*)(wsb);                       // 150,994,944
  u16* qkv1 = (u16*)(wsb + 150994944);          // 150,994,944
  u16* qkv2 = (u16*)(wsb + 301989888);          // 150,994,944
  u16* wbf1 = (u16*)(wsb + 452984832);          // 221,184
  u16* wbf2 = (u16*)(wsb + 453206016);          // 221,184
  float* norms = (float*)(wsb + 453427200);     // 24,576
  float* G = (float*)(wsb + 453451776);         // 589,824
  u16* WcatBf = (u16*)(wsb + 454041600);        // 2,359,296
  float* gp = (float*)(wsb + 456400896);        // 9,437,184  -> end 465,838,080

  const int dwblocks = (int)(((size_t)NB * NC3 * NHW) / (256 * 8));

  wcast_kernel<<<(NC3 * NCH + 255) / 256, 256, 0, stream>>>(w_qkv1, w_qkv2, wbf1, wbf2);
  conv_mfma_kernel<<<dim3(128, 3, NB), 256, 0, stream>>>(x1, wbf1, pre);
  dwconv_kernel<<<dwblocks, 256, 0, stream>>>(pre, w_dw1, qkv1);
  conv_mfma_kernel<<<dim3(128, 3, NB), 256, 0, stream>>>(x2, wbf2, pre);
  dwconv_kernel<<<dwblocks, 256, 0, stream>>>(pre, w_dw2, qkv2);
  norms_kernel<<<4 * NB * NCH, 256, 0, stream>>>(qkv1, qkv2, norms);
  gram_mfma_kernel<<<dim3(16, NHEADS, NB), 256, 0, stream>>>(qkv1, qkv2, gp);
  gram_reduce_kernel<<<NB * NHEADS, 256, 0, stream>>>(gp, G);
  softmax_wcat_kernel<<<NB * NHEADS, 256, 0, stream>>>(G, norms, temperature, beta, w_proj, WcatBf);
  final_mfma_kernel<<<dim3(128, 3, NB), 256, 0, stream>>>(qkv1, qkv2, WcatBf, out);
}

// Round 4
// 572.976 us; speedup vs baseline: 4.6100x; 1.0019x over previous
//
#include <hip/hip_runtime.h>

typedef unsigned short u16;
typedef unsigned int u32;

#define NB 8
#define NCH 192
#define NC3 576
#define NHW 16384
#define NHEADS 8

typedef __attribute__((ext_vector_type(8))) short s16x8;
typedef __attribute__((ext_vector_type(4))) float f32x4;

__device__ __forceinline__ float bf2f(u32 h) {
  return __uint_as_float(h << 16);
}
__device__ __forceinline__ u16 f2bf(float f) {
  u32 u = __float_as_uint(f);
  u = (u + 0x7fffu + ((u >> 16) & 1u)) >> 16;
  return (u16)u;
}
__device__ __forceinline__ u32 pk2(u16 a, u16 b) { return (u32)a | ((u32)b << 16); }

// XOR swizzle within a 128-byte LDS row.
__device__ __forceinline__ int swz(int row) { return ((row >> 1) & 7) << 4; }

__device__ __forceinline__ void gl_lds16(const void* g, void* s) {
  __builtin_amdgcn_global_load_lds((const __attribute__((address_space(1))) unsigned int*)g,
                                   (__attribute__((address_space(3))) unsigned int*)s, 16, 0, 0);
}

// ---------------------------------------------------------------------------
// cast conv weights fp32 -> bf16; zero norms2 accumulator
// ---------------------------------------------------------------------------
__global__ __launch_bounds__(256) void wcast_kernel(
    const float* __restrict__ w1, const float* __restrict__ w2,
    u16* __restrict__ o1, u16* __restrict__ o2, float* __restrict__ norms2) {
  int i = blockIdx.x * 256 + threadIdx.x;
  if (i < NC3 * NCH) {
    o1[i] = f2bf(w1[i]);
    o2[i] = f2bf(w2[i]);
  }
  if (i < 4 * NB * NCH) norms2[i] = 0.f;
}

// ---------------------------------------------------------------------------
// conv1x1 MFMA: pre[b][o][n] = sum_k w[o][k] * x[b][k][n]
// 1-D grid, XCD-chunk swizzled, o-tile innermost: the 3 o-tiles sharing an
// x-tile run adjacently on the same XCD -> x fetched once into that L2.
// ---------------------------------------------------------------------------
__global__ __launch_bounds__(256) void conv_mfma_kernel(
    const float* __restrict__ x, const u16* __restrict__ wbf, u16* __restrict__ pre) {
  __shared__ u16 Al[192 * 64];  // [o][k] rows of 128B, swizzled
  __shared__ u16 Bl[128 * 64];  // [n][k] rows of 128B, swizzled
  const int bid = blockIdx.x;                      // 3072 blocks
  const int id = (bid & 7) * 384 + (bid >> 3);     // bijective XCD chunk
  const int b = id / 384;
  const int rr = id % 384;
  const int nbase = (rr / 3) * 128;
  const int obase = (rr % 3) * 192;
  const int tid = threadIdx.x;
  const int w = tid >> 6, l = tid & 63;
  const int wr = w >> 1, wc = w & 1;

  f32x4 acc[6][4];
#pragma unroll
  for (int m = 0; m < 6; ++m)
#pragma unroll
    for (int nf = 0; nf < 4; ++nf) acc[m][nf] = (f32x4)0.f;

  for (int kb = 0; kb < 192; kb += 64) {
#pragma unroll
    for (int i = 0; i < 6; ++i) {
      const int grp = i * 4 + w;
      const int row = grp * 8 + (l >> 3);
      const int cb = ((l & 7) * 16) ^ swz(row);
      const char* src = (const char*)wbf + (size_t)(obase + row) * 384 + kb * 2 + cb;
      gl_lds16(src, (char*)Al + grp * 1024);
    }
#pragma unroll
    for (int pi = 0; pi < 2; ++pi) {
      const int p = pi * 256 + tid;
      const int ng = p & 31, kg = p >> 5;
      const float* xr = x + (((size_t)b * NCH + kb + kg * 4) << 14) + nbase + ng * 4;
      float4 f0 = *(const float4*)(xr);
      float4 f1 = *(const float4*)(xr + NHW);
      float4 f2 = *(const float4*)(xr + 2 * NHW);
      float4 f3 = *(const float4*)(xr + 3 * NHW);
      u16 e0[4] = {f2bf(f0.x), f2bf(f0.y), f2bf(f0.z), f2bf(f0.w)};
      u16 e1[4] = {f2bf(f1.x), f2bf(f1.y), f2bf(f1.z), f2bf(f1.w)};
      u16 e2[4] = {f2bf(f2.x), f2bf(f2.y), f2bf(f2.z), f2bf(f2.w)};
      u16 e3[4] = {f2bf(f3.x), f2bf(f3.y), f2bf(f3.z), f2bf(f3.w)};
#pragma unroll
      for (int nn = 0; nn < 4; ++nn) {
        const int row = ng * 4 + nn;
        const int cb = (kg * 8) ^ swz(row);
        *(uint2*)((char*)Bl + row * 128 + cb) = make_uint2(pk2(e0[nn], e1[nn]), pk2(e2[nn], e3[nn]));
      }
    }
    __syncthreads();
#pragma unroll
    for (int kk = 0; kk < 2; ++kk) {
      s16x8 a[6], bv[4];
      const int cbk = kk * 64 + (l >> 4) * 16;
#pragma unroll
      for (int m = 0; m < 6; ++m) {
        const int rowA = wr * 96 + m * 16 + (l & 15);
        a[m] = *(const s16x8*)((const char*)Al + rowA * 128 + (cbk ^ swz(rowA)));
      }
#pragma unroll
      for (int nf = 0; nf < 4; ++nf) {
        const int rowB = wc * 64 + nf * 16 + (l & 15);
        bv[nf] = *(const s16x8*)((const char*)Bl + rowB * 128 + (cbk ^ swz(rowB)));
      }
#pragma unroll
      for (int m = 0; m < 6; ++m)
#pragma unroll
        for (int nf = 0; nf < 4; ++nf)
          acc[m][nf] = __builtin_amdgcn_mfma_f32_16x16x32_bf16(a[m], bv[nf], acc[m][nf], 0, 0, 0);
    }
    __syncthreads();
  }
#pragma unroll
  for (int m = 0; m < 6; ++m) {
    const int o = obase + wr * 96 + m * 16 + (l >> 4) * 4;
#pragma unroll
    for (int nf = 0; nf < 4; ++nf) {
      const int n = nbase + wc * 64 + nf * 16 + (l & 15);
#pragma unroll
      for (int r = 0; r < 4; ++r)
        pre[(((size_t)b * NC3 + o + r) << 14) + n] = f2bf(acc[m][nf][r]);
    }
  }
}

// ---------------------------------------------------------------------------
// depthwise 3x3 (8 px/thread) + fused sum-of-squares for q,k planes.
// Each block covers one (b,c) slice (16 rows) -> one atomicAdd per block.
// ---------------------------------------------------------------------------
__global__ __launch_bounds__(256) void dwconv_kernel(
    const u16* __restrict__ in, const float* __restrict__ wdw, u16* __restrict__ out,
    float* __restrict__ norms2, const int mod) {
  const size_t t = (size_t)blockIdx.x * 256 + threadIdx.x;
  const int tid = threadIdx.x;
  const int xc = (int)(t & 15);
  const int yy = (int)((t >> 4) & 127);
  const int bc = (int)(t >> 11);
  const int c = bc % NC3;
  const int b = bc / NC3;
  const u16* p = in + ((size_t)bc << 14);
  const float* wc = wdw + c * 9;
  const int x0 = xc * 8;

  float a[3][10];
#pragma unroll
  for (int r = 0; r < 3; ++r) {
    const int y2 = yy + r - 1;
    if ((unsigned)y2 < 128u) {
      const u16* row = p + (y2 << 7);
      uint4 v = *(const uint4*)(row + x0);
      a[r][1] = bf2f(v.x & 0xffff); a[r][2] = bf2f(v.x >> 16);
      a[r][3] = bf2f(v.y & 0xffff); a[r][4] = bf2f(v.y >> 16);
      a[r][5] = bf2f(v.z & 0xffff); a[r][6] = bf2f(v.z >> 16);
      a[r][7] = bf2f(v.w & 0xffff); a[r][8] = bf2f(v.w >> 16);
      a[r][0] = (x0 > 0) ? bf2f(row[x0 - 1]) : 0.f;
      a[r][9] = (x0 + 8 < 128) ? bf2f(row[x0 + 8]) : 0.f;
    } else {
#pragma unroll
      for (int j = 0; j < 10; ++j) a[r][j] = 0.f;
    }
  }
  const float w00 = wc[0], w01 = wc[1], w02 = wc[2];
  const float w10 = wc[3], w11 = wc[4], w12 = wc[5];
  const float w20 = wc[6], w21 = wc[7], w22 = wc[8];
  u16 o[8];
  float ssq = 0.f;
#pragma unroll
  for (int j = 0; j < 8; ++j) {
    float s = a[0][j] * w00;
    s = fmaf(a[0][j + 1], w01, s);
    s = fmaf(a[0][j + 2], w02, s);
    s = fmaf(a[1][j], w10, s);
    s = fmaf(a[1][j + 1], w11, s);
    s = fmaf(a[1][j + 2], w12, s);
    s = fmaf(a[2][j], w20, s);
    s = fmaf(a[2][j + 1], w21, s);
    s = fmaf(a[2][j + 2], w22, s);
    ssq = fmaf(s, s, ssq);
    o[j] = f2bf(s);
  }
  *(uint4*)(out + (t << 3)) =
      make_uint4(pk2(o[0], o[1]), pk2(o[2], o[3]), pk2(o[4], o[5]), pk2(o[6], o[7]));

  if (c < 384) {
#pragma unroll
    for (int off = 32; off > 0; off >>= 1) ssq += __shfl_down(ssq, off, 64);
    __shared__ float red[4];
    if ((tid & 63) == 0) red[tid >> 6] = ssq;
    __syncthreads();
    if (tid == 0) {
      const int tt = (c < 192) ? mod : 2 + mod;
      atomicAdd(&norms2[(tt * NB + b) * NCH + (c % NCH)], red[0] + red[1] + red[2] + red[3]);
    }
  }
}

// ---------------------------------------------------------------------------
// Gram via MFMA, fragments direct from global (NT: contraction over n).
// ---------------------------------------------------------------------------
__global__ __launch_bounds__(256) void gram_mfma_kernel(
    const u16* __restrict__ qkv1, const u16* __restrict__ qkv2, float* __restrict__ gp) {
  const int nc = blockIdx.x, h = blockIdx.y, b = blockIdx.z;
  const int tid = threadIdx.x;
  const int w = tid >> 6, l = tid & 63;

  const u16* qp[3];
  const u16* kp[3];
#pragma unroll
  for (int m = 0; m < 3; ++m) {
    const int rq = m * 16 + (l & 15);
    const int cc = h * 24 + (rq < 24 ? rq : rq - 24);
    const u16* basep = (rq < 24) ? qkv1 : qkv2;
    qp[m] = basep + (((size_t)b * NC3 + cc) << 14);
    kp[m] = basep + (((size_t)b * NC3 + 192 + cc) << 14);
  }
  const int kbase = nc * 1024 + w * 256 + (l >> 4) * 8;

  f32x4 acc[3][3];
#pragma unroll
  for (int m = 0; m < 3; ++m)
#pragma unroll
    for (int nf = 0; nf < 3; ++nf) acc[m][nf] = (f32x4)0.f;

  for (int t = 0; t < 8; ++t) {
    const int ko = kbase + t * 32;
    s16x8 a[3], bv[3];
#pragma unroll
    for (int m = 0; m < 3; ++m) {
      a[m] = *(const s16x8*)(qp[m] + ko);
      bv[m] = *(const s16x8*)(kp[m] + ko);
    }
#pragma unroll
    for (int m = 0; m < 3; ++m)
#pragma unroll
      for (int nf = 0; nf < 3; ++nf)
        acc[m][nf] = __builtin_amdgcn_mfma_f32_16x16x32_bf16(a[m], bv[nf], acc[m][nf], 0, 0, 0);
  }

  __shared__ float red[4][48][48];
#pragma unroll
  for (int m = 0; m < 3; ++m)
#pragma unroll
    for (int nf = 0; nf < 3; ++nf)
#pragma unroll
      for (int r = 0; r < 4; ++r)
        red[w][m * 16 + (l >> 4) * 4 + r][nf * 16 + (l & 15)] = acc[m][nf][r];
  __syncthreads();
  float* dst = gp + ((((size_t)b * 8 + h) * 16 + nc) * 2304);
  for (int e = tid; e < 2304; e += 256) {
    const int rr = e / 48, cc = e % 48;
    dst[e] = red[0][rr][cc] + red[1][rr][cc] + red[2][rr][cc] + red[3][rr][cc];
  }
}

__global__ __launch_bounds__(256) void gram_reduce_kernel(
    const float* __restrict__ gp, float* __restrict__ G) {
  const int bh = blockIdx.x;
  for (int e = threadIdx.x; e < 2304; e += 256) {
    float s = 0.f;
    for (int p = 0; p < 16; ++p) s += gp[((size_t)bh * 16 + p) * 2304 + e];
    G[(size_t)bh * 2304 + e] = s;
  }
}

// ---------------------------------------------------------------------------
// softmax (4x 24x24 per b,h) + fused weights, bf16 output
// ---------------------------------------------------------------------------
__global__ __launch_bounds__(256) void softmax_wcat_kernel(
    const float* __restrict__ G, const float* __restrict__ norms2,
    const float* __restrict__ temperature, const float* __restrict__ beta,
    const float* __restrict__ wproj, u16* __restrict__ Wcat) {
  const int bh = blockIdx.x;
  const int b = bh >> 3, h = bh & 7;
  __shared__ float sm[4][24][24];
  __shared__ float nrm[4][24];
  const int tid = threadIdx.x;
  if (tid < 96) {
    int t = tid / 24, ci = tid % 24;
    nrm[t][ci] = fmaxf(sqrtf(norms2[(t * NB + b) * NCH + h * 24 + ci]), 1e-12f);
  }
  __syncthreads();
  const float T = temperature[h];
  const float sigB = 1.f / (1.f + expf(-beta[0]));
  if (tid < 96) {
    const int m = tid / 24, r = tid % 24;
    const float* Gb = G + (size_t)bh * 2304;
    const int gr = (m >= 2) ? 24 + r : r;
    const int gc0 = (m == 1 || m == 2) ? 24 : 0;
    const float* qn = (m >= 2) ? nrm[1] : nrm[0];
    const float* kn = (m == 1 || m == 2) ? nrm[3] : nrm[2];
    const float sign = (m == 0 || m == 2) ? 1.f : -1.f;
    const float qs = sign * T / qn[r];
    float L[24], mx = -1e30f;
#pragma unroll
    for (int cc = 0; cc < 24; ++cc) {
      L[cc] = Gb[gr * 48 + gc0 + cc] * qs / kn[cc];
      mx = fmaxf(mx, L[cc]);
    }
    float ssum = 0.f;
#pragma unroll
    for (int cc = 0; cc < 24; ++cc) {
      L[cc] = expf(L[cc] - mx);
      ssum += L[cc];
    }
    const float inv = 1.f / ssum;
#pragma unroll
    for (int cc = 0; cc < 24; ++cc) sm[m][r][cc] = L[cc] * inv;
  }
  __syncthreads();
  for (int e = tid; e < 384 * 48; e += 256) {
    const int o = e / 48, dc = e % 48;
    const int part = dc / 24, d = dc % 24;
    const int oc = (o < 192) ? o : o - 192;
    int m;
    float scale;
    if (o < 192) { m = part ? 1 : 0; scale = part ? 1.f : sigB; }
    else         { m = part ? 2 : 3; scale = part ? sigB : 1.f; }
    float s = 0.f;
#pragma unroll
    for (int ci = 0; ci < 24; ++ci) s += wproj[oc * 192 + h * 24 + ci] * sm[m][ci][d];
    Wcat[((size_t)b * 384 + o) * 384 + part * 192 + h * 24 + d] = f2bf(s * scale);
  }
}

// ---------------------------------------------------------------------------
// final GEMM MFMA: out[b][o][n] = sum_j Wcat[b][o][j] * V[j][n]
// XCD-chunk swizzled, o-tile innermost (V-tile L2 reuse).
// ---------------------------------------------------------------------------
__global__ __launch_bounds__(256) void final_mfma_kernel(
    const u16* __restrict__ qkv1, const u16* __restrict__ qkv2,
    const u16* __restrict__ Wcat, float* __restrict__ out) {
  __shared__ u16 Al[128 * 64];
  __shared__ u16 Bl[128 * 64];
  const int bid = blockIdx.x;                      // 3072 blocks
  const int id = (bid & 7) * 384 + (bid >> 3);
  const int b = id / 384;
  const int rr2 = id % 384;
  const int nbase = (rr2 / 3) * 128;
  const int obase = (rr2 % 3) * 128;
  const int tid = threadIdx.x;
  const int w = tid >> 6, l = tid & 63;
  const int wr = w >> 1, wc = w & 1;

  f32x4 acc[4][4];
#pragma unroll
  for (int m = 0; m < 4; ++m)
#pragma unroll
    for (int nf = 0; nf < 4; ++nf) acc[m][nf] = (f32x4)0.f;

  for (int kb = 0; kb < 384; kb += 64) {
#pragma unroll
    for (int i = 0; i < 4; ++i) {
      const int grp = i * 4 + w;
      const int row = grp * 8 + (l >> 3);
      const int cb = ((l & 7) * 16) ^ swz(row);
      const char* src = (const char*)Wcat + ((size_t)b * 384 + obase + row) * 768 + kb * 2 + cb;
      gl_lds16(src, (char*)Al + grp * 1024);
    }
    const u16* vbase = (kb < 192) ? qkv1 + (((size_t)b * NC3 + 384 + kb) << 14)
                                  : qkv2 + (((size_t)b * NC3 + 384 + kb - 192) << 14);
#pragma unroll
    for (int pi = 0; pi < 2; ++pi) {
      const int p = pi * 256 + tid;
      const int ng = p & 31, kg = p >> 5;
      const u16* vr = vbase + (((size_t)kg * 4) << 14) + nbase + ng * 4;
      uint2 r0 = *(const uint2*)(vr);
      uint2 r1 = *(const uint2*)(vr + NHW);
      uint2 r2 = *(const uint2*)(vr + 2 * NHW);
      uint2 r3 = *(const uint2*)(vr + 3 * NHW);
      u16 e0[4] = {(u16)(r0.x & 0xffff), (u16)(r0.x >> 16), (u16)(r0.y & 0xffff), (u16)(r0.y >> 16)};
      u16 e1[4] = {(u16)(r1.x & 0xffff), (u16)(r1.x >> 16), (u16)(r1.y & 0xffff), (u16)(r1.y >> 16)};
      u16 e2[4] = {(u16)(r2.x & 0xffff), (u16)(r2.x >> 16), (u16)(r2.y & 0xffff), (u16)(r2.y >> 16)};
      u16 e3[4] = {(u16)(r3.x & 0xffff), (u16)(r3.x >> 16), (u16)(r3.y & 0xffff), (u16)(r3.y >> 16)};
#pragma unroll
      for (int nn = 0; nn < 4; ++nn) {
        const int row = ng * 4 + nn;
        const int cb = (kg * 8) ^ swz(row);
        *(uint2*)((char*)Bl + row * 128 + cb) = make_uint2(pk2(e0[nn], e1[nn]), pk2(e2[nn], e3[nn]));
      }
    }
    __syncthreads();
#pragma unroll
    for (int kk = 0; kk < 2; ++kk) {
      s16x8 a[4], bv[4];
      const int cbk = kk * 64 + (l >> 4) * 16;
#pragma unroll
      for (int m = 0; m < 4; ++m) {
        const int rowA = wr * 64 + m * 16 + (l & 15);
        a[m] = *(const s16x8*)((const char*)Al + rowA * 128 + (cbk ^ swz(rowA)));
      }
#pragma unroll
      for (int nf = 0; nf < 4; ++nf) {
        const int rowB = wc * 64 + nf * 16 + (l & 15);
        bv[nf] = *(const s16x8*)((const char*)Bl + rowB * 128 + (cbk ^ swz(rowB)));
      }
#pragma unroll
      for (int m = 0; m < 4; ++m)
#pragma unroll
        for (int nf = 0; nf < 4; ++nf)
          acc[m][nf] = __builtin_amdgcn_mfma_f32_16x16x32_bf16(a[m], bv[nf], acc[m][nf], 0, 0, 0);
    }
    __syncthreads();
  }
#pragma unroll
  for (int m = 0; m < 4; ++m) {
    const int o = obase + wr * 64 + m * 16 + (l >> 4) * 4;
#pragma unroll
    for (int nf = 0; nf < 4; ++nf) {
      const int n = nbase + wc * 64 + nf * 16 + (l & 15);
#pragma unroll
      for (int r = 0; r < 4; ++r) {
        const int oo = o + r;
        float* dst = (oo < 192) ? out + (((size_t)b * NCH + oo) << 14) + n
                                : out + 25165824 + (((size_t)b * NCH + oo - 192) << 14) + n;
        *dst = acc[m][nf][r];
      }
    }
  }
}

// ---------------------------------------------------------------------------
extern "C" void kernel_launch(void* const* d_in, const int* in_sizes, int n_in,
                              void* d_out, int out_size, void* d_ws, size_t ws_size,
                              hipStream_t stream) {
  (void)in_sizes; (void)n_in; (void)out_size; (void)ws_size;
  const float* x1 = (const float*)d_in[0];
  const float* x2 = (const float*)d_in[1];
  const float* w_qkv1 = (const float*)d_in[2];
  const float* w_dw1 = (const float*)d_in[3];
  const float* w_qkv2 = (const float*)d_in[4];
  const float* w_dw2 = (const float*)d_in[5];
  const float* w_proj = (const float*)d_in[6];
  const float* temperature = (const float*)d_in[7];
  const float* beta = (const float*)d_in[8];
  float* out = (float*)d_out;

  char* wsb = (char*)d_ws;
  u16* pre = (u16*)(wsb);                       // 150,994,944
  u16* qkv1 = (u16*)(wsb + 150994944);          // 150,994,944
  u16* qkv2 = (u16*)(wsb + 301989888);          // 150,994,944
  u16* wbf1 = (u16*)(wsb + 452984832);          // 221,184
  u16* wbf2 = (u16*)(wsb + 453206016);          // 221,184
  float* norms2 = (float*)(wsb + 453427200);    // 24,576
  float* G = (float*)(wsb + 453451776);         // 589,824
  u16* WcatBf = (u16*)(wsb + 454041600);        // 2,359,296
  float* gp = (float*)(wsb + 456400896);        // 9,437,184  -> end 465,838,080

  const int dwblocks = (int)(((size_t)NB * NC3 * NHW) / (256 * 8));

  wcast_kernel<<<(NC3 * NCH + 255) / 256, 256, 0, stream>>>(w_qkv1, w_qkv2, wbf1, wbf2, norms2);
  conv_mfma_kernel<<<3072, 256, 0, stream>>>(x1, wbf1, pre);
  dwconv_kernel<<<dwblocks, 256, 0, stream>>>(pre, w_dw1, qkv1, norms2, 0);
  conv_mfma_kernel<<<3072, 256, 0, stream>>>(x2, wbf2, pre);
  dwconv_kernel<<<dwblocks, 256, 0, stream>>>(pre, w_dw2, qkv2, norms2, 1);
  gram_mfma_kernel<<<dim3(16, NHEADS, NB), 256, 0, stream>>>(qkv1, qkv2, gp);
  gram_reduce_kernel<<<NB * NHEADS, 256, 0, stream>>>(gp, G);
  softmax_wcat_kernel<<<NB * NHEADS, 256, 0, stream>>>(G, norms2, temperature, beta, w_proj, WcatBf);
  final_mfma_kernel<<<3072, 256, 0, stream>>>(qkv1, qkv2, WcatBf, out);
}

// Round 5
// 569.865 us; speedup vs baseline: 4.6351x; 1.0055x over previous
//
#include <hip/hip_runtime.h>

typedef unsigned short u16;
typedef unsigned int u32;

#define NB 8
#define NCH 192
#define NC3 576
#define NHW 16384
#define NHEADS 8

typedef __attribute__((ext_vector_type(8))) short s16x8;
typedef __attribute__((ext_vector_type(4))) float f32x4;

__device__ __forceinline__ float bf2f(u32 h) {
  return __uint_as_float(h << 16);
}
__device__ __forceinline__ u16 f2bf(float f) {
  u32 u = __float_as_uint(f);
  u = (u + 0x7fffu + ((u >> 16) & 1u)) >> 16;
  return (u16)u;
}
__device__ __forceinline__ u32 pk2(u16 a, u16 b) { return (u32)a | ((u32)b << 16); }

// XOR swizzle within a 128-byte LDS row.
__device__ __forceinline__ int swz(int row) { return ((row >> 1) & 7) << 4; }

__device__ __forceinline__ void gl_lds16(const void* g, void* s) {
  __builtin_amdgcn_global_load_lds((const __attribute__((address_space(1))) unsigned int*)g,
                                   (__attribute__((address_space(3))) unsigned int*)s, 16, 0, 0);
}

// ---------------------------------------------------------------------------
// cast conv weights fp32 -> bf16; zero norms2 accumulator
// ---------------------------------------------------------------------------
__global__ __launch_bounds__(256) void wcast_kernel(
    const float* __restrict__ w1, const float* __restrict__ w2,
    u16* __restrict__ o1, u16* __restrict__ o2, float* __restrict__ norms2) {
  int i = blockIdx.x * 256 + threadIdx.x;
  if (i < NC3 * NCH) {
    o1[i] = f2bf(w1[i]);
    o2[i] = f2bf(w2[i]);
  }
  if (i < 4 * NB * NCH) norms2[i] = 0.f;
}

// ---------------------------------------------------------------------------
// conv1x1 MFMA: pre[b][o][n] = sum_k w[o][k] * x[b][k][n]
// XCD-chunk swizzled; LDS-transpose epilogue -> dwordx4 stores.
// ---------------------------------------------------------------------------
__global__ __launch_bounds__(256) void conv_mfma_kernel(
    const float* __restrict__ x, const u16* __restrict__ wbf, u16* __restrict__ pre) {
  __shared__ char smem[40960];
  u16* Al = (u16*)smem;            // 192*64 u16 = 24576 B
  u16* Bl = (u16*)(smem + 24576);  // 128*64 u16 = 16384 B
  const int bid = blockIdx.x;                      // 3072 blocks
  const int id = (bid & 7) * 384 + (bid >> 3);     // bijective XCD chunk
  const int b = id / 384;
  const int rr = id % 384;
  const int nbase = (rr / 3) * 128;
  const int obase = (rr % 3) * 192;
  const int tid = threadIdx.x;
  const int w = tid >> 6, l = tid & 63;
  const int wr = w >> 1, wc = w & 1;

  f32x4 acc[6][4];
#pragma unroll
  for (int m = 0; m < 6; ++m)
#pragma unroll
    for (int nf = 0; nf < 4; ++nf) acc[m][nf] = (f32x4)0.f;

  for (int kb = 0; kb < 192; kb += 64) {
#pragma unroll
    for (int i = 0; i < 6; ++i) {
      const int grp = i * 4 + w;
      const int row = grp * 8 + (l >> 3);
      const int cb = ((l & 7) * 16) ^ swz(row);
      const char* src = (const char*)wbf + (size_t)(obase + row) * 384 + kb * 2 + cb;
      gl_lds16(src, (char*)Al + grp * 1024);
    }
#pragma unroll
    for (int pi = 0; pi < 2; ++pi) {
      const int p = pi * 256 + tid;
      const int ng = p & 31, kg = p >> 5;
      const float* xr = x + (((size_t)b * NCH + kb + kg * 4) << 14) + nbase + ng * 4;
      float4 f0 = *(const float4*)(xr);
      float4 f1 = *(const float4*)(xr + NHW);
      float4 f2 = *(const float4*)(xr + 2 * NHW);
      float4 f3 = *(const float4*)(xr + 3 * NHW);
      u16 e0[4] = {f2bf(f0.x), f2bf(f0.y), f2bf(f0.z), f2bf(f0.w)};
      u16 e1[4] = {f2bf(f1.x), f2bf(f1.y), f2bf(f1.z), f2bf(f1.w)};
      u16 e2[4] = {f2bf(f2.x), f2bf(f2.y), f2bf(f2.z), f2bf(f2.w)};
      u16 e3[4] = {f2bf(f3.x), f2bf(f3.y), f2bf(f3.z), f2bf(f3.w)};
#pragma unroll
      for (int nn = 0; nn < 4; ++nn) {
        const int row = ng * 4 + nn;
        const int cb = (kg * 8) ^ swz(row);
        *(uint2*)((char*)Bl + row * 128 + cb) = make_uint2(pk2(e0[nn], e1[nn]), pk2(e2[nn], e3[nn]));
      }
    }
    __syncthreads();
#pragma unroll
    for (int kk = 0; kk < 2; ++kk) {
      s16x8 a[6], bv[4];
      const int cbk = kk * 64 + (l >> 4) * 16;
#pragma unroll
      for (int m = 0; m < 6; ++m) {
        const int rowA = wr * 96 + m * 16 + (l & 15);
        a[m] = *(const s16x8*)((const char*)Al + rowA * 128 + (cbk ^ swz(rowA)));
      }
#pragma unroll
      for (int nf = 0; nf < 4; ++nf) {
        const int rowB = wc * 64 + nf * 16 + (l & 15);
        bv[nf] = *(const s16x8*)((const char*)Bl + rowB * 128 + (cbk ^ swz(rowB)));
      }
#pragma unroll
      for (int m = 0; m < 6; ++m)
#pragma unroll
        for (int nf = 0; nf < 4; ++nf)
          acc[m][nf] = __builtin_amdgcn_mfma_f32_16x16x32_bf16(a[m], bv[nf], acc[m][nf], 0, 0, 0);
    }
    __syncthreads();
  }
  // epilogue: per-wave LDS transpose ([16][72] u16), then 16B stores.
  u16* cw = (u16*)(smem) + w * 16 * 72;
#pragma unroll
  for (int m = 0; m < 6; ++m) {
#pragma unroll
    for (int nf = 0; nf < 4; ++nf)
#pragma unroll
      for (int r = 0; r < 4; ++r)
        cw[((l >> 4) * 4 + r) * 72 + nf * 16 + (l & 15)] = f2bf(acc[m][nf][r]);
#pragma unroll
    for (int p = 0; p < 2; ++p) {
      const int chunk = p * 64 + l;
      const int row = chunk >> 3, cg = chunk & 7;
      uint4 v = *(const uint4*)(cw + row * 72 + cg * 8);
      const int o = obase + wr * 96 + m * 16 + row;
      const int n = nbase + wc * 64 + cg * 8;
      *(uint4*)(pre + (((size_t)b * NC3 + o) << 14) + n) = v;
    }
  }
}

// ---------------------------------------------------------------------------
// depthwise 3x3 (8 px/thread) + fused sum-of-squares for q,k planes.
// ---------------------------------------------------------------------------
__global__ __launch_bounds__(256) void dwconv_kernel(
    const u16* __restrict__ in, const float* __restrict__ wdw, u16* __restrict__ out,
    float* __restrict__ norms2, const int mod) {
  const size_t t = (size_t)blockIdx.x * 256 + threadIdx.x;
  const int tid = threadIdx.x;
  const int xc = (int)(t & 15);
  const int yy = (int)((t >> 4) & 127);
  const int bc = (int)(t >> 11);
  const int c = bc % NC3;
  const int b = bc / NC3;
  const u16* p = in + ((size_t)bc << 14);
  const float* wc = wdw + c * 9;
  const int x0 = xc * 8;

  float a[3][10];
#pragma unroll
  for (int r = 0; r < 3; ++r) {
    const int y2 = yy + r - 1;
    if ((unsigned)y2 < 128u) {
      const u16* row = p + (y2 << 7);
      uint4 v = *(const uint4*)(row + x0);
      a[r][1] = bf2f(v.x & 0xffff); a[r][2] = bf2f(v.x >> 16);
      a[r][3] = bf2f(v.y & 0xffff); a[r][4] = bf2f(v.y >> 16);
      a[r][5] = bf2f(v.z & 0xffff); a[r][6] = bf2f(v.z >> 16);
      a[r][7] = bf2f(v.w & 0xffff); a[r][8] = bf2f(v.w >> 16);
      a[r][0] = (x0 > 0) ? bf2f(row[x0 - 1]) : 0.f;
      a[r][9] = (x0 + 8 < 128) ? bf2f(row[x0 + 8]) : 0.f;
    } else {
#pragma unroll
      for (int j = 0; j < 10; ++j) a[r][j] = 0.f;
    }
  }
  const float w00 = wc[0], w01 = wc[1], w02 = wc[2];
  const float w10 = wc[3], w11 = wc[4], w12 = wc[5];
  const float w20 = wc[6], w21 = wc[7], w22 = wc[8];
  u16 o[8];
  float ssq = 0.f;
#pragma unroll
  for (int j = 0; j < 8; ++j) {
    float s = a[0][j] * w00;
    s = fmaf(a[0][j + 1], w01, s);
    s = fmaf(a[0][j + 2], w02, s);
    s = fmaf(a[1][j], w10, s);
    s = fmaf(a[1][j + 1], w11, s);
    s = fmaf(a[1][j + 2], w12, s);
    s = fmaf(a[2][j], w20, s);
    s = fmaf(a[2][j + 1], w21, s);
    s = fmaf(a[2][j + 2], w22, s);
    ssq = fmaf(s, s, ssq);
    o[j] = f2bf(s);
  }
  *(uint4*)(out + (t << 3)) =
      make_uint4(pk2(o[0], o[1]), pk2(o[2], o[3]), pk2(o[4], o[5]), pk2(o[6], o[7]));

  if (c < 384) {
#pragma unroll
    for (int off = 32; off > 0; off >>= 1) ssq += __shfl_down(ssq, off, 64);
    __shared__ float red[4];
    if ((tid & 63) == 0) red[tid >> 6] = ssq;
    __syncthreads();
    if (tid == 0) {
      const int tt = (c < 192) ? mod : 2 + mod;
      atomicAdd(&norms2[(tt * NB + b) * NCH + (c % NCH)], red[0] + red[1] + red[2] + red[3]);
    }
  }
}

// ---------------------------------------------------------------------------
// Gram via MFMA, fragments direct from global (NT: contraction over n).
// ---------------------------------------------------------------------------
__global__ __launch_bounds__(256) void gram_mfma_kernel(
    const u16* __restrict__ qkv1, const u16* __restrict__ qkv2, float* __restrict__ gp) {
  const int nc = blockIdx.x, h = blockIdx.y, b = blockIdx.z;
  const int tid = threadIdx.x;
  const int w = tid >> 6, l = tid & 63;

  const u16* qp[3];
  const u16* kp[3];
#pragma unroll
  for (int m = 0; m < 3; ++m) {
    const int rq = m * 16 + (l & 15);
    const int cc = h * 24 + (rq < 24 ? rq : rq - 24);
    const u16* basep = (rq < 24) ? qkv1 : qkv2;
    qp[m] = basep + (((size_t)b * NC3 + cc) << 14);
    kp[m] = basep + (((size_t)b * NC3 + 192 + cc) << 14);
  }
  const int kbase = nc * 1024 + w * 256 + (l >> 4) * 8;

  f32x4 acc[3][3];
#pragma unroll
  for (int m = 0; m < 3; ++m)
#pragma unroll
    for (int nf = 0; nf < 3; ++nf) acc[m][nf] = (f32x4)0.f;

  for (int t = 0; t < 8; ++t) {
    const int ko = kbase + t * 32;
    s16x8 a[3], bv[3];
#pragma unroll
    for (int m = 0; m < 3; ++m) {
      a[m] = *(const s16x8*)(qp[m] + ko);
      bv[m] = *(const s16x8*)(kp[m] + ko);
    }
#pragma unroll
    for (int m = 0; m < 3; ++m)
#pragma unroll
      for (int nf = 0; nf < 3; ++nf)
        acc[m][nf] = __builtin_amdgcn_mfma_f32_16x16x32_bf16(a[m], bv[nf], acc[m][nf], 0, 0, 0);
  }

  __shared__ float red[4][48][48];
#pragma unroll
  for (int m = 0; m < 3; ++m)
#pragma unroll
    for (int nf = 0; nf < 3; ++nf)
#pragma unroll
      for (int r = 0; r < 4; ++r)
        red[w][m * 16 + (l >> 4) * 4 + r][nf * 16 + (l & 15)] = acc[m][nf][r];
  __syncthreads();
  float* dst = gp + ((((size_t)b * 8 + h) * 16 + nc) * 2304);
  for (int e = tid; e < 2304; e += 256) {
    const int rr = e / 48, cc = e % 48;
    dst[e] = red[0][rr][cc] + red[1][rr][cc] + red[2][rr][cc] + red[3][rr][cc];
  }
}

__global__ __launch_bounds__(256) void gram_reduce_kernel(
    const float* __restrict__ gp, float* __restrict__ G) {
  const int bh = blockIdx.x;
  for (int e = threadIdx.x; e < 2304; e += 256) {
    float s = 0.f;
    for (int p = 0; p < 16; ++p) s += gp[((size_t)bh * 16 + p) * 2304 + e];
    G[(size_t)bh * 2304 + e] = s;
  }
}

// ---------------------------------------------------------------------------
// softmax (4x 24x24 per b,h) + fused weights, bf16 output
// ---------------------------------------------------------------------------
__global__ __launch_bounds__(256) void softmax_wcat_kernel(
    const float* __restrict__ G, const float* __restrict__ norms2,
    const float* __restrict__ temperature, const float* __restrict__ beta,
    const float* __restrict__ wproj, u16* __restrict__ Wcat) {
  const int bh = blockIdx.x;
  const int b = bh >> 3, h = bh & 7;
  __shared__ float sm[4][24][24];
  __shared__ float nrm[4][24];
  const int tid = threadIdx.x;
  if (tid < 96) {
    int t = tid / 24, ci = tid % 24;
    nrm[t][ci] = fmaxf(sqrtf(norms2[(t * NB + b) * NCH + h * 24 + ci]), 1e-12f);
  }
  __syncthreads();
  const float T = temperature[h];
  const float sigB = 1.f / (1.f + expf(-beta[0]));
  if (tid < 96) {
    const int m = tid / 24, r = tid % 24;
    const float* Gb = G + (size_t)bh * 2304;
    const int gr = (m >= 2) ? 24 + r : r;
    const int gc0 = (m == 1 || m == 2) ? 24 : 0;
    const float* qn = (m >= 2) ? nrm[1] : nrm[0];
    const float* kn = (m == 1 || m == 2) ? nrm[3] : nrm[2];
    const float sign = (m == 0 || m == 2) ? 1.f : -1.f;
    const float qs = sign * T / qn[r];
    float L[24], mx = -1e30f;
#pragma unroll
    for (int cc = 0; cc < 24; ++cc) {
      L[cc] = Gb[gr * 48 + gc0 + cc] * qs / kn[cc];
      mx = fmaxf(mx, L[cc]);
    }
    float ssum = 0.f;
#pragma unroll
    for (int cc = 0; cc < 24; ++cc) {
      L[cc] = expf(L[cc] - mx);
      ssum += L[cc];
    }
    const float inv = 1.f / ssum;
#pragma unroll
    for (int cc = 0; cc < 24; ++cc) sm[m][r][cc] = L[cc] * inv;
  }
  __syncthreads();
  for (int e = tid; e < 384 * 48; e += 256) {
    const int o = e / 48, dc = e % 48;
    const int part = dc / 24, d = dc % 24;
    const int oc = (o < 192) ? o : o - 192;
    int m;
    float scale;
    if (o < 192) { m = part ? 1 : 0; scale = part ? 1.f : sigB; }
    else         { m = part ? 2 : 3; scale = part ? sigB : 1.f; }
    float s = 0.f;
#pragma unroll
    for (int ci = 0; ci < 24; ++ci) s += wproj[oc * 192 + h * 24 + ci] * sm[m][ci][d];
    Wcat[((size_t)b * 384 + o) * 384 + part * 192 + h * 24 + d] = f2bf(s * scale);
  }
}

// ---------------------------------------------------------------------------
// final GEMM MFMA: out[b][o][n] = sum_j Wcat[b][o][j] * V[j][n]
// LDS-transpose epilogue -> float4 stores.
// ---------------------------------------------------------------------------
__global__ __launch_bounds__(256) void final_mfma_kernel(
    const u16* __restrict__ qkv1, const u16* __restrict__ qkv2,
    const u16* __restrict__ Wcat, float* __restrict__ out) {
  __shared__ char smem[32768];
  u16* Al = (u16*)smem;            // 128*64 u16
  u16* Bl = (u16*)(smem + 16384);  // 128*64 u16
  const int bid = blockIdx.x;                      // 3072 blocks
  const int id = (bid & 7) * 384 + (bid >> 3);
  const int b = id / 384;
  const int rr2 = id % 384;
  const int nbase = (rr2 / 3) * 128;
  const int obase = (rr2 % 3) * 128;
  const int tid = threadIdx.x;
  const int w = tid >> 6, l = tid & 63;
  const int wr = w >> 1, wc = w & 1;

  f32x4 acc[4][4];
#pragma unroll
  for (int m = 0; m < 4; ++m)
#pragma unroll
    for (int nf = 0; nf < 4; ++nf) acc[m][nf] = (f32x4)0.f;

  for (int kb = 0; kb < 384; kb += 64) {
#pragma unroll
    for (int i = 0; i < 4; ++i) {
      const int grp = i * 4 + w;
      const int row = grp * 8 + (l >> 3);
      const int cb = ((l & 7) * 16) ^ swz(row);
      const char* src = (const char*)Wcat + ((size_t)b * 384 + obase + row) * 768 + kb * 2 + cb;
      gl_lds16(src, (char*)Al + grp * 1024);
    }
    const u16* vbase = (kb < 192) ? qkv1 + (((size_t)b * NC3 + 384 + kb) << 14)
                                  : qkv2 + (((size_t)b * NC3 + 384 + kb - 192) << 14);
#pragma unroll
    for (int pi = 0; pi < 2; ++pi) {
      const int p = pi * 256 + tid;
      const int ng = p & 31, kg = p >> 5;
      const u16* vr = vbase + (((size_t)kg * 4) << 14) + nbase + ng * 4;
      uint2 r0 = *(const uint2*)(vr);
      uint2 r1 = *(const uint2*)(vr + NHW);
      uint2 r2 = *(const uint2*)(vr + 2 * NHW);
      uint2 r3 = *(const uint2*)(vr + 3 * NHW);
      u16 e0[4] = {(u16)(r0.x & 0xffff), (u16)(r0.x >> 16), (u16)(r0.y & 0xffff), (u16)(r0.y >> 16)};
      u16 e1[4] = {(u16)(r1.x & 0xffff), (u16)(r1.x >> 16), (u16)(r1.y & 0xffff), (u16)(r1.y >> 16)};
      u16 e2[4] = {(u16)(r2.x & 0xffff), (u16)(r2.x >> 16), (u16)(r2.y & 0xffff), (u16)(r2.y >> 16)};
      u16 e3[4] = {(u16)(r3.x & 0xffff), (u16)(r3.x >> 16), (u16)(r3.y & 0xffff), (u16)(r3.y >> 16)};
#pragma unroll
      for (int nn = 0; nn < 4; ++nn) {
        const int row = ng * 4 + nn;
        const int cb = (kg * 8) ^ swz(row);
        *(uint2*)((char*)Bl + row * 128 + cb) = make_uint2(pk2(e0[nn], e1[nn]), pk2(e2[nn], e3[nn]));
      }
    }
    __syncthreads();
#pragma unroll
    for (int kk = 0; kk < 2; ++kk) {
      s16x8 a[4], bv[4];
      const int cbk = kk * 64 + (l >> 4) * 16;
#pragma unroll
      for (int m = 0; m < 4; ++m) {
        const int rowA = wr * 64 + m * 16 + (l & 15);
        a[m] = *(const s16x8*)((const char*)Al + rowA * 128 + (cbk ^ swz(rowA)));
      }
#pragma unroll
      for (int nf = 0; nf < 4; ++nf) {
        const int rowB = wc * 64 + nf * 16 + (l & 15);
        bv[nf] = *(const s16x8*)((const char*)Bl + rowB * 128 + (cbk ^ swz(rowB)));
      }
#pragma unroll
      for (int m = 0; m < 4; ++m)
#pragma unroll
        for (int nf = 0; nf < 4; ++nf)
          acc[m][nf] = __builtin_amdgcn_mfma_f32_16x16x32_bf16(a[m], bv[nf], acc[m][nf], 0, 0, 0);
    }
    __syncthreads();
  }
  // epilogue: per-wave LDS transpose ([16][68] f32), then float4 stores.
  float* cw = (float*)(smem + w * 4352);
#pragma unroll
  for (int m = 0; m < 4; ++m) {
#pragma unroll
    for (int nf = 0; nf < 4; ++nf)
#pragma unroll
      for (int r = 0; r < 4; ++r)
        cw[((l >> 4) * 4 + r) * 68 + nf * 16 + (l & 15)] = acc[m][nf][r];
#pragma unroll
    for (int p = 0; p < 4; ++p) {
      const int chunk = p * 64 + l;
      const int row = chunk >> 4, cg = chunk & 15;
      float4 v = *(const float4*)(cw + row * 68 + cg * 4);
      const int o = obase + wr * 64 + m * 16 + row;
      const int n = nbase + wc * 64 + cg * 4;
      float* dst = (o < 192) ? out + (((size_t)b * NCH + o) << 14) + n
                             : out + 25165824 + (((size_t)b * NCH + o - 192) << 14) + n;
      *(float4*)dst = v;
    }
  }
}

// ---------------------------------------------------------------------------
extern "C" void kernel_launch(void* const* d_in, const int* in_sizes, int n_in,
                              void* d_out, int out_size, void* d_ws, size_t ws_size,
                              hipStream_t stream) {
  (void)in_sizes; (void)n_in; (void)out_size; (void)ws_size;
  const float* x1 = (const float*)d_in[0];
  const float* x2 = (const float*)d_in[1];
  const float* w_qkv1 = (const float*)d_in[2];
  const float* w_dw1 = (const float*)d_in[3];
  const float* w_qkv2 = (const float*)d_in[4];
  const float* w_dw2 = (const float*)d_in[5];
  const float* w_proj = (const float*)d_in[6];
  const float* temperature = (const float*)d_in[7];
  const float* beta = (const float*)d_in[8];
  float* out = (float*)d_out;

  char* wsb = (char*)d_ws;
  u16* pre = (u16*)(wsb);                       // 150,994,944
  u16* qkv1 = (u16*)(wsb + 150994944);          // 150,994,944
  u16* qkv2 = (u16*)(wsb + 301989888);          // 150,994,944
  u16* wbf1 = (u16*)(wsb + 452984832);          // 221,184
  u16* wbf2 = (u16*)(wsb + 453206016);          // 221,184
  float* norms2 = (float*)(wsb + 453427200);    // 24,576
  float* G = (float*)(wsb + 453451776);         // 589,824
  u16* WcatBf = (u16*)(wsb + 454041600);        // 2,359,296
  float* gp = (float*)(wsb + 456400896);        // 9,437,184  -> end 465,838,080

  const int dwblocks = (int)(((size_t)NB * NC3 * NHW) / (256 * 8));

  wcast_kernel<<<(NC3 * NCH + 255) / 256, 256, 0, stream>>>(w_qkv1, w_qkv2, wbf1, wbf2, norms2);
  conv_mfma_kernel<<<3072, 256, 0, stream>>>(x1, wbf1, pre);
  dwconv_kernel<<<dwblocks, 256, 0, stream>>>(pre, w_dw1, qkv1, norms2, 0);
  conv_mfma_kernel<<<3072, 256, 0, stream>>>(x2, wbf2, pre);
  dwconv_kernel<<<dwblocks, 256, 0, stream>>>(pre, w_dw2, qkv2, norms2, 1);
  gram_mfma_kernel<<<dim3(16, NHEADS, NB), 256, 0, stream>>>(qkv1, qkv2, gp);
  gram_reduce_kernel<<<NB * NHEADS, 256, 0, stream>>>(gp, G);
  softmax_wcat_kernel<<<NB * NHEADS, 256, 0, stream>>>(G, norms2, temperature, beta, w_proj, WcatBf);
  final_mfma_kernel<<<3072, 256, 0, stream>>>(qkv1, qkv2, WcatBf, out);
}

// Round 6
// 518.366 us; speedup vs baseline: 5.0956x; 1.0993x over previous
//
#include <hip/hip_runtime.h>

typedef unsigned short u16;
typedef unsigned int u32;

#define NB 8
#define NCH 192
#define NC3 576
#define NHW 16384
#define NHEADS 8

typedef __attribute__((ext_vector_type(8))) short s16x8;
typedef __attribute__((ext_vector_type(4))) float f32x4;

__device__ __forceinline__ float bf2f(u32 h) {
  return __uint_as_float(h << 16);
}
__device__ __forceinline__ u16 f2bf(float f) {
  u32 u = __float_as_uint(f);
  u = (u + 0x7fffu + ((u >> 16) & 1u)) >> 16;
  return (u16)u;
}
__device__ __forceinline__ u32 pk2(u16 a, u16 b) { return (u32)a | ((u32)b << 16); }

// XOR swizzle within a 128-byte LDS row.
__device__ __forceinline__ int swz(int row) { return ((row >> 1) & 7) << 4; }

__device__ __forceinline__ void gl_lds16(const void* g, void* s) {
  __builtin_amdgcn_global_load_lds((const __attribute__((address_space(1))) unsigned int*)g,
                                   (__attribute__((address_space(3))) unsigned int*)s, 16, 0, 0);
}

// ---------------------------------------------------------------------------
// cast conv weights fp32 -> bf16; zero norms2 accumulator
// ---------------------------------------------------------------------------
__global__ __launch_bounds__(256) void wcast_kernel(
    const float* __restrict__ w1, const float* __restrict__ w2,
    u16* __restrict__ o1, u16* __restrict__ o2, float* __restrict__ norms2) {
  int i = blockIdx.x * 256 + threadIdx.x;
  if (i < NC3 * NCH) {
    o1[i] = f2bf(w1[i]);
    o2[i] = f2bf(w2[i]);
  }
  if (i < 4 * NB * NCH) norms2[i] = 0.f;
}

// ---------------------------------------------------------------------------
// conv1x1 MFMA: pre[b][o][n] = sum_k w[o][k] * x[b][k][n]
// XCD-chunk swizzled; LDS-transpose epilogue -> dwordx4 stores.
// ---------------------------------------------------------------------------
__global__ __launch_bounds__(256) void conv_mfma_kernel(
    const float* __restrict__ x, const u16* __restrict__ wbf, u16* __restrict__ pre) {
  __shared__ char smem[40960];
  u16* Al = (u16*)smem;            // 192*64 u16 = 24576 B
  u16* Bl = (u16*)(smem + 24576);  // 128*64 u16 = 16384 B
  const int bid = blockIdx.x;                      // 3072 blocks
  const int id = (bid & 7) * 384 + (bid >> 3);     // bijective XCD chunk
  const int b = id / 384;
  const int rr = id % 384;
  const int nbase = (rr / 3) * 128;
  const int obase = (rr % 3) * 192;
  const int tid = threadIdx.x;
  const int w = tid >> 6, l = tid & 63;
  const int wr = w >> 1, wc = w & 1;

  f32x4 acc[6][4];
#pragma unroll
  for (int m = 0; m < 6; ++m)
#pragma unroll
    for (int nf = 0; nf < 4; ++nf) acc[m][nf] = (f32x4)0.f;

  for (int kb = 0; kb < 192; kb += 64) {
#pragma unroll
    for (int i = 0; i < 6; ++i) {
      const int grp = i * 4 + w;
      const int row = grp * 8 + (l >> 3);
      const int cb = ((l & 7) * 16) ^ swz(row);
      const char* src = (const char*)wbf + (size_t)(obase + row) * 384 + kb * 2 + cb;
      gl_lds16(src, (char*)Al + grp * 1024);
    }
#pragma unroll
    for (int pi = 0; pi < 2; ++pi) {
      const int p = pi * 256 + tid;
      const int ng = p & 31, kg = p >> 5;
      const float* xr = x + (((size_t)b * NCH + kb + kg * 4) << 14) + nbase + ng * 4;
      float4 f0 = *(const float4*)(xr);
      float4 f1 = *(const float4*)(xr + NHW);
      float4 f2 = *(const float4*)(xr + 2 * NHW);
      float4 f3 = *(const float4*)(xr + 3 * NHW);
      u16 e0[4] = {f2bf(f0.x), f2bf(f0.y), f2bf(f0.z), f2bf(f0.w)};
      u16 e1[4] = {f2bf(f1.x), f2bf(f1.y), f2bf(f1.z), f2bf(f1.w)};
      u16 e2[4] = {f2bf(f2.x), f2bf(f2.y), f2bf(f2.z), f2bf(f2.w)};
      u16 e3[4] = {f2bf(f3.x), f2bf(f3.y), f2bf(f3.z), f2bf(f3.w)};
#pragma unroll
      for (int nn = 0; nn < 4; ++nn) {
        const int row = ng * 4 + nn;
        const int cb = (kg * 8) ^ swz(row);
        *(uint2*)((char*)Bl + row * 128 + cb) = make_uint2(pk2(e0[nn], e1[nn]), pk2(e2[nn], e3[nn]));
      }
    }
    __syncthreads();
#pragma unroll
    for (int kk = 0; kk < 2; ++kk) {
      s16x8 a[6], bv[4];
      const int cbk = kk * 64 + (l >> 4) * 16;
#pragma unroll
      for (int m = 0; m < 6; ++m) {
        const int rowA = wr * 96 + m * 16 + (l & 15);
        a[m] = *(const s16x8*)((const char*)Al + rowA * 128 + (cbk ^ swz(rowA)));
      }
#pragma unroll
      for (int nf = 0; nf < 4; ++nf) {
        const int rowB = wc * 64 + nf * 16 + (l & 15);
        bv[nf] = *(const s16x8*)((const char*)Bl + rowB * 128 + (cbk ^ swz(rowB)));
      }
#pragma unroll
      for (int m = 0; m < 6; ++m)
#pragma unroll
        for (int nf = 0; nf < 4; ++nf)
          acc[m][nf] = __builtin_amdgcn_mfma_f32_16x16x32_bf16(a[m], bv[nf], acc[m][nf], 0, 0, 0);
    }
    __syncthreads();
  }
  // epilogue: per-wave LDS transpose ([16][72] u16), then 16B stores.
  u16* cw = (u16*)(smem) + w * 16 * 72;
#pragma unroll
  for (int m = 0; m < 6; ++m) {
#pragma unroll
    for (int nf = 0; nf < 4; ++nf)
#pragma unroll
      for (int r = 0; r < 4; ++r)
        cw[((l >> 4) * 4 + r) * 72 + nf * 16 + (l & 15)] = f2bf(acc[m][nf][r]);
#pragma unroll
    for (int p = 0; p < 2; ++p) {
      const int chunk = p * 64 + l;
      const int row = chunk >> 3, cg = chunk & 7;
      uint4 v = *(const uint4*)(cw + row * 72 + cg * 8);
      const int o = obase + wr * 96 + m * 16 + row;
      const int n = nbase + wc * 64 + cg * 8;
      *(uint4*)(pre + (((size_t)b * NC3 + o) << 14) + n) = v;
    }
  }
}

// ---------------------------------------------------------------------------
// depthwise 3x3 (8 px/thread) + fused sum-of-squares for q,k planes.
// x-edges via cross-lane shfl (no scalar loads).
// ---------------------------------------------------------------------------
__global__ __launch_bounds__(256) void dwconv_kernel(
    const u16* __restrict__ in, const float* __restrict__ wdw, u16* __restrict__ out,
    float* __restrict__ norms2, const int mod) {
  const size_t t = (size_t)blockIdx.x * 256 + threadIdx.x;
  const int tid = threadIdx.x;
  const int l = tid & 63;
  const int xc = (int)(t & 15);
  const int yy = (int)((t >> 4) & 127);
  const int bc = (int)(t >> 11);
  const int c = bc % NC3;
  const int b = bc / NC3;
  const u16* p = in + ((size_t)bc << 14);
  const float* wc = wdw + c * 9;
  const int x0 = xc * 8;

  float a[3][10];
#pragma unroll
  for (int r = 0; r < 3; ++r) {
    const int y2 = yy + r - 1;
    if ((unsigned)y2 < 128u) {
      const u16* row = p + (y2 << 7);
      uint4 v = *(const uint4*)(row + x0);
      a[r][1] = bf2f(v.x & 0xffff); a[r][2] = bf2f(v.x >> 16);
      a[r][3] = bf2f(v.y & 0xffff); a[r][4] = bf2f(v.y >> 16);
      a[r][5] = bf2f(v.z & 0xffff); a[r][6] = bf2f(v.z >> 16);
      a[r][7] = bf2f(v.w & 0xffff); a[r][8] = bf2f(v.w >> 16);
    } else {
#pragma unroll
      for (int j = 1; j < 9; ++j) a[r][j] = 0.f;
    }
    // x-edges from neighbor lanes: lane xc-1 holds x0-1 as its elem 8,
    // lane xc+1 holds x0+8 as its elem 1. Image border -> 0.
    const float lf = __shfl(a[r][8], (l - 1) & 63, 64);
    const float rt = __shfl(a[r][1], (l + 1) & 63, 64);
    a[r][0] = (xc > 0) ? lf : 0.f;
    a[r][9] = (xc < 15) ? rt : 0.f;
  }
  const float w00 = wc[0], w01 = wc[1], w02 = wc[2];
  const float w10 = wc[3], w11 = wc[4], w12 = wc[5];
  const float w20 = wc[6], w21 = wc[7], w22 = wc[8];
  u16 o[8];
  float ssq = 0.f;
#pragma unroll
  for (int j = 0; j < 8; ++j) {
    float s = a[0][j] * w00;
    s = fmaf(a[0][j + 1], w01, s);
    s = fmaf(a[0][j + 2], w02, s);
    s = fmaf(a[1][j], w10, s);
    s = fmaf(a[1][j + 1], w11, s);
    s = fmaf(a[1][j + 2], w12, s);
    s = fmaf(a[2][j], w20, s);
    s = fmaf(a[2][j + 1], w21, s);
    s = fmaf(a[2][j + 2], w22, s);
    ssq = fmaf(s, s, ssq);
    o[j] = f2bf(s);
  }
  *(uint4*)(out + (t << 3)) =
      make_uint4(pk2(o[0], o[1]), pk2(o[2], o[3]), pk2(o[4], o[5]), pk2(o[6], o[7]));

  if (c < 384) {
#pragma unroll
    for (int off = 32; off > 0; off >>= 1) ssq += __shfl_down(ssq, off, 64);
    __shared__ float red[4];
    if ((tid & 63) == 0) red[tid >> 6] = ssq;
    __syncthreads();
    if (tid == 0) {
      const int tt = (c < 192) ? mod : 2 + mod;
      atomicAdd(&norms2[(tt * NB + b) * NCH + (c % NCH)], red[0] + red[1] + red[2] + red[3]);
    }
  }
}

// ---------------------------------------------------------------------------
// Gram via MFMA, fragments direct from global (NT: contraction over n).
// ---------------------------------------------------------------------------
__global__ __launch_bounds__(256) void gram_mfma_kernel(
    const u16* __restrict__ qkv1, const u16* __restrict__ qkv2, float* __restrict__ gp) {
  const int nc = blockIdx.x, h = blockIdx.y, b = blockIdx.z;
  const int tid = threadIdx.x;
  const int w = tid >> 6, l = tid & 63;

  const u16* qp[3];
  const u16* kp[3];
#pragma unroll
  for (int m = 0; m < 3; ++m) {
    const int rq = m * 16 + (l & 15);
    const int cc = h * 24 + (rq < 24 ? rq : rq - 24);
    const u16* basep = (rq < 24) ? qkv1 : qkv2;
    qp[m] = basep + (((size_t)b * NC3 + cc) << 14);
    kp[m] = basep + (((size_t)b * NC3 + 192 + cc) << 14);
  }
  const int kbase = nc * 1024 + w * 256 + (l >> 4) * 8;

  f32x4 acc[3][3];
#pragma unroll
  for (int m = 0; m < 3; ++m)
#pragma unroll
    for (int nf = 0; nf < 3; ++nf) acc[m][nf] = (f32x4)0.f;

  for (int t = 0; t < 8; ++t) {
    const int ko = kbase + t * 32;
    s16x8 a[3], bv[3];
#pragma unroll
    for (int m = 0; m < 3; ++m) {
      a[m] = *(const s16x8*)(qp[m] + ko);
      bv[m] = *(const s16x8*)(kp[m] + ko);
    }
#pragma unroll
    for (int m = 0; m < 3; ++m)
#pragma unroll
      for (int nf = 0; nf < 3; ++nf)
        acc[m][nf] = __builtin_amdgcn_mfma_f32_16x16x32_bf16(a[m], bv[nf], acc[m][nf], 0, 0, 0);
  }

  __shared__ float red[4][48][48];
#pragma unroll
  for (int m = 0; m < 3; ++m)
#pragma unroll
    for (int nf = 0; nf < 3; ++nf)
#pragma unroll
      for (int r = 0; r < 4; ++r)
        red[w][m * 16 + (l >> 4) * 4 + r][nf * 16 + (l & 15)] = acc[m][nf][r];
  __syncthreads();
  float* dst = gp + ((((size_t)b * 8 + h) * 16 + nc) * 2304);
  for (int e = tid; e < 2304; e += 256) {
    const int rr = e / 48, cc = e % 48;
    dst[e] = red[0][rr][cc] + red[1][rr][cc] + red[2][rr][cc] + red[3][rr][cc];
  }
}

__global__ __launch_bounds__(256) void gram_reduce_kernel(
    const float* __restrict__ gp, float* __restrict__ G) {
  const int bh = blockIdx.x;
  for (int e = threadIdx.x; e < 2304; e += 256) {
    float s = 0.f;
    for (int p = 0; p < 16; ++p) s += gp[((size_t)bh * 16 + p) * 2304 + e];
    G[(size_t)bh * 2304 + e] = s;
  }
}

// ---------------------------------------------------------------------------
// softmax (4x 24x24 per b,h) + fused weights, bf16 output
// ---------------------------------------------------------------------------
__global__ __launch_bounds__(256) void softmax_wcat_kernel(
    const float* __restrict__ G, const float* __restrict__ norms2,
    const float* __restrict__ temperature, const float* __restrict__ beta,
    const float* __restrict__ wproj, u16* __restrict__ Wcat) {
  const int bh = blockIdx.x;
  const int b = bh >> 3, h = bh & 7;
  __shared__ float sm[4][24][24];
  __shared__ float nrm[4][24];
  const int tid = threadIdx.x;
  if (tid < 96) {
    int t = tid / 24, ci = tid % 24;
    nrm[t][ci] = fmaxf(sqrtf(norms2[(t * NB + b) * NCH + h * 24 + ci]), 1e-12f);
  }
  __syncthreads();
  const float T = temperature[h];
  const float sigB = 1.f / (1.f + expf(-beta[0]));
  if (tid < 96) {
    const int m = tid / 24, r = tid % 24;
    const float* Gb = G + (size_t)bh * 2304;
    const int gr = (m >= 2) ? 24 + r : r;
    const int gc0 = (m == 1 || m == 2) ? 24 : 0;
    const float* qn = (m >= 2) ? nrm[1] : nrm[0];
    const float* kn = (m == 1 || m == 2) ? nrm[3] : nrm[2];
    const float sign = (m == 0 || m == 2) ? 1.f : -1.f;
    const float qs = sign * T / qn[r];
    float L[24], mx = -1e30f;
#pragma unroll
    for (int cc = 0; cc < 24; ++cc) {
      L[cc] = Gb[gr * 48 + gc0 + cc] * qs / kn[cc];
      mx = fmaxf(mx, L[cc]);
    }
    float ssum = 0.f;
#pragma unroll
    for (int cc = 0; cc < 24; ++cc) {
      L[cc] = expf(L[cc] - mx);
      ssum += L[cc];
    }
    const float inv = 1.f / ssum;
#pragma unroll
    for (int cc = 0; cc < 24; ++cc) sm[m][r][cc] = L[cc] * inv;
  }
  __syncthreads();
  for (int e = tid; e < 384 * 48; e += 256) {
    const int o = e / 48, dc = e % 48;
    const int part = dc / 24, d = dc % 24;
    const int oc = (o < 192) ? o : o - 192;
    int m;
    float scale;
    if (o < 192) { m = part ? 1 : 0; scale = part ? 1.f : sigB; }
    else         { m = part ? 2 : 3; scale = part ? sigB : 1.f; }
    float s = 0.f;
#pragma unroll
    for (int ci = 0; ci < 24; ++ci) s += wproj[oc * 192 + h * 24 + ci] * sm[m][ci][d];
    Wcat[((size_t)b * 384 + o) * 384 + part * 192 + h * 24 + d] = f2bf(s * scale);
  }
}

// ---------------------------------------------------------------------------
// final GEMM MFMA: out[b][o][n] = sum_j Wcat[b][o][j] * V[j][n]
// LDS-transpose epilogue -> float4 stores.
// ---------------------------------------------------------------------------
__global__ __launch_bounds__(256) void final_mfma_kernel(
    const u16* __restrict__ qkv1, const u16* __restrict__ qkv2,
    const u16* __restrict__ Wcat, float* __restrict__ out) {
  __shared__ char smem[32768];
  u16* Al = (u16*)smem;            // 128*64 u16
  u16* Bl = (u16*)(smem + 16384);  // 128*64 u16
  const int bid = blockIdx.x;                      // 3072 blocks
  const int id = (bid & 7) * 384 + (bid >> 3);
  const int b = id / 384;
  const int rr2 = id % 384;
  const int nbase = (rr2 / 3) * 128;
  const int obase = (rr2 % 3) * 128;
  const int tid = threadIdx.x;
  const int w = tid >> 6, l = tid & 63;
  const int wr = w >> 1, wc = w & 1;

  f32x4 acc[4][4];
#pragma unroll
  for (int m = 0; m < 4; ++m)
#pragma unroll
    for (int nf = 0; nf < 4; ++nf) acc[m][nf] = (f32x4)0.f;

  for (int kb = 0; kb < 384; kb += 64) {
#pragma unroll
    for (int i = 0; i < 4; ++i) {
      const int grp = i * 4 + w;
      const int row = grp * 8 + (l >> 3);
      const int cb = ((l & 7) * 16) ^ swz(row);
      const char* src = (const char*)Wcat + ((size_t)b * 384 + obase + row) * 768 + kb * 2 + cb;
      gl_lds16(src, (char*)Al + grp * 1024);
    }
    const u16* vbase = (kb < 192) ? qkv1 + (((size_t)b * NC3 + 384 + kb) << 14)
                                  : qkv2 + (((size_t)b * NC3 + 384 + kb - 192) << 14);
#pragma unroll
    for (int pi = 0; pi < 2; ++pi) {
      const int p = pi * 256 + tid;
      const int ng = p & 31, kg = p >> 5;
      const u16* vr = vbase + (((size_t)kg * 4) << 14) + nbase + ng * 4;
      uint2 r0 = *(const uint2*)(vr);
      uint2 r1 = *(const uint2*)(vr + NHW);
      uint2 r2 = *(const uint2*)(vr + 2 * NHW);
      uint2 r3 = *(const uint2*)(vr + 3 * NHW);
      u16 e0[4] = {(u16)(r0.x & 0xffff), (u16)(r0.x >> 16), (u16)(r0.y & 0xffff), (u16)(r0.y >> 16)};
      u16 e1[4] = {(u16)(r1.x & 0xffff), (u16)(r1.x >> 16), (u16)(r1.y & 0xffff), (u16)(r1.y >> 16)};
      u16 e2[4] = {(u16)(r2.x & 0xffff), (u16)(r2.x >> 16), (u16)(r2.y & 0xffff), (u16)(r2.y >> 16)};
      u16 e3[4] = {(u16)(r3.x & 0xffff), (u16)(r3.x >> 16), (u16)(r3.y & 0xffff), (u16)(r3.y >> 16)};
#pragma unroll
      for (int nn = 0; nn < 4; ++nn) {
        const int row = ng * 4 + nn;
        const int cb = (kg * 8) ^ swz(row);
        *(uint2*)((char*)Bl + row * 128 + cb) = make_uint2(pk2(e0[nn], e1[nn]), pk2(e2[nn], e3[nn]));
      }
    }
    __syncthreads();
#pragma unroll
    for (int kk = 0; kk < 2; ++kk) {
      s16x8 a[4], bv[4];
      const int cbk = kk * 64 + (l >> 4) * 16;
#pragma unroll
      for (int m = 0; m < 4; ++m) {
        const int rowA = wr * 64 + m * 16 + (l & 15);
        a[m] = *(const s16x8*)((const char*)Al + rowA * 128 + (cbk ^ swz(rowA)));
      }
#pragma unroll
      for (int nf = 0; nf < 4; ++nf) {
        const int rowB = wc * 64 + nf * 16 + (l & 15);
        bv[nf] = *(const s16x8*)((const char*)Bl + rowB * 128 + (cbk ^ swz(rowB)));
      }
#pragma unroll
      for (int m = 0; m < 4; ++m)
#pragma unroll
        for (int nf = 0; nf < 4; ++nf)
          acc[m][nf] = __builtin_amdgcn_mfma_f32_16x16x32_bf16(a[m], bv[nf], acc[m][nf], 0, 0, 0);
    }
    __syncthreads();
  }
  // epilogue: per-wave LDS transpose ([16][68] f32), then float4 stores.
  float* cw = (float*)(smem + w * 4352);
#pragma unroll
  for (int m = 0; m < 4; ++m) {
#pragma unroll
    for (int nf = 0; nf < 4; ++nf)
#pragma unroll
      for (int r = 0; r < 4; ++r)
        cw[((l >> 4) * 4 + r) * 68 + nf * 16 + (l & 15)] = acc[m][nf][r];
#pragma unroll
    for (int p = 0; p < 4; ++p) {
      const int chunk = p * 64 + l;
      const int row = chunk >> 4, cg = chunk & 15;
      float4 v = *(const float4*)(cw + row * 68 + cg * 4);
      const int o = obase + wr * 64 + m * 16 + row;
      const int n = nbase + wc * 64 + cg * 4;
      float* dst = (o < 192) ? out + (((size_t)b * NCH + o) << 14) + n
                             : out + 25165824 + (((size_t)b * NCH + o - 192) << 14) + n;
      *(float4*)dst = v;
    }
  }
}

// ---------------------------------------------------------------------------
extern "C" void kernel_launch(void* const* d_in, const int* in_sizes, int n_in,
                              void* d_out, int out_size, void* d_ws, size_t ws_size,
                              hipStream_t stream) {
  (void)in_sizes; (void)n_in; (void)out_size; (void)ws_size;
  const float* x1 = (const float*)d_in[0];
  const float* x2 = (const float*)d_in[1];
  const float* w_qkv1 = (const float*)d_in[2];
  const float* w_dw1 = (const float*)d_in[3];
  const float* w_qkv2 = (const float*)d_in[4];
  const float* w_dw2 = (const float*)d_in[5];
  const float* w_proj = (const float*)d_in[6];
  const float* temperature = (const float*)d_in[7];
  const float* beta = (const float*)d_in[8];
  float* out = (float*)d_out;

  char* wsb = (char*)d_ws;
  u16* pre = (u16*)(wsb);                       // 150,994,944
  u16* qkv1 = (u16*)(wsb + 150994944);          // 150,994,944
  u16* qkv2 = (u16*)(wsb + 301989888);          // 150,994,944
  u16* wbf1 = (u16*)(wsb + 452984832);          // 221,184
  u16* wbf2 = (u16*)(wsb + 453206016);          // 221,184
  float* norms2 = (float*)(wsb + 453427200);    // 24,576
  float* G = (float*)(wsb + 453451776);         // 589,824
  u16* WcatBf = (u16*)(wsb + 454041600);        // 2,359,296
  float* gp = (float*)(wsb + 456400896);        // 9,437,184  -> end 465,838,080

  const int dwblocks = (int)(((size_t)NB * NC3 * NHW) / (256 * 8));

  wcast_kernel<<<(NC3 * NCH + 255) / 256, 256, 0, stream>>>(w_qkv1, w_qkv2, wbf1, wbf2, norms2);
  conv_mfma_kernel<<<3072, 256, 0, stream>>>(x1, wbf1, pre);
  dwconv_kernel<<<dwblocks, 256, 0, stream>>>(pre, w_dw1, qkv1, norms2, 0);
  conv_mfma_kernel<<<3072, 256, 0, stream>>>(x2, wbf2, pre);
  dwconv_kernel<<<dwblocks, 256, 0, stream>>>(pre, w_dw2, qkv2, norms2, 1);
  gram_mfma_kernel<<<dim3(16, NHEADS, NB), 256, 0, stream>>>(qkv1, qkv2, gp);
  gram_reduce_kernel<<<NB * NHEADS, 256, 0, stream>>>(gp, G);
  softmax_wcat_kernel<<<NB * NHEADS, 256, 0, stream>>>(G, norms2, temperature, beta, w_proj, WcatBf);
  final_mfma_kernel<<<3072, 256, 0, stream>>>(qkv1, qkv2, WcatBf, out);
}

// Round 7
// 517.353 us; speedup vs baseline: 5.1056x; 1.0020x over previous
//
#include <hip/hip_runtime.h>

typedef unsigned short u16;
typedef unsigned int u32;

#define NB 8
#define NCH 192
#define NC3 576
#define NHW 16384
#define NHEADS 8

typedef __attribute__((ext_vector_type(8))) short s16x8;
typedef __attribute__((ext_vector_type(4))) float f32x4;

__device__ __forceinline__ float bf2f(u32 h) {
  return __uint_as_float(h << 16);
}
__device__ __forceinline__ u16 f2bf(float f) {
  u32 u = __float_as_uint(f);
  u = (u + 0x7fffu + ((u >> 16) & 1u)) >> 16;
  return (u16)u;
}
__device__ __forceinline__ u32 pk2(u16 a, u16 b) { return (u32)a | ((u32)b << 16); }

// XOR swizzle within a 128-byte LDS row.
__device__ __forceinline__ int swz(int row) { return ((row >> 1) & 7) << 4; }

__device__ __forceinline__ void gl_lds16(const void* g, void* s) {
  __builtin_amdgcn_global_load_lds((const __attribute__((address_space(1))) unsigned int*)g,
                                   (__attribute__((address_space(3))) unsigned int*)s, 16, 0, 0);
}

// ---------------------------------------------------------------------------
// cast conv weights fp32 -> bf16; zero norms2 accumulator
// ---------------------------------------------------------------------------
__global__ __launch_bounds__(256) void wcast_kernel(
    const float* __restrict__ w1, const float* __restrict__ w2,
    u16* __restrict__ o1, u16* __restrict__ o2, float* __restrict__ norms2) {
  int i = blockIdx.x * 256 + threadIdx.x;
  if (i < NC3 * NCH) {
    o1[i] = f2bf(w1[i]);
    o2[i] = f2bf(w2[i]);
  }
  if (i < 4 * NB * NCH) norms2[i] = 0.f;
}

// ---------------------------------------------------------------------------
// conv1x1 MFMA, 2-phase pipelined: A (weights) double-buffered via gl_lds,
// B (x, reg-staged transpose) single-buffered with issue-early/write-late.
// LDS: A0 @0 (24576), A1 @24576, B @49152 (16384) = 64 KB.
// ---------------------------------------------------------------------------
__device__ __forceinline__ void conv_b_load(const float* __restrict__ x, int b, int nbase,
                                            int kb, int tid, float4 (&fB)[2][4]) {
#pragma unroll
  for (int pi = 0; pi < 2; ++pi) {
    const int p = pi * 256 + tid;
    const int ng = p & 31, kg = p >> 5;
    const float* xr = x + (((size_t)b * NCH + kb + kg * 4) << 14) + nbase + ng * 4;
    fB[pi][0] = *(const float4*)(xr);
    fB[pi][1] = *(const float4*)(xr + NHW);
    fB[pi][2] = *(const float4*)(xr + 2 * NHW);
    fB[pi][3] = *(const float4*)(xr + 3 * NHW);
  }
}

__device__ __forceinline__ void conv_b_write(char* smem, int tid, const float4 (&fB)[2][4]) {
#pragma unroll
  for (int pi = 0; pi < 2; ++pi) {
    const int p = pi * 256 + tid;
    const int ng = p & 31, kg = p >> 5;
    u16 e0[4] = {f2bf(fB[pi][0].x), f2bf(fB[pi][0].y), f2bf(fB[pi][0].z), f2bf(fB[pi][0].w)};
    u16 e1[4] = {f2bf(fB[pi][1].x), f2bf(fB[pi][1].y), f2bf(fB[pi][1].z), f2bf(fB[pi][1].w)};
    u16 e2[4] = {f2bf(fB[pi][2].x), f2bf(fB[pi][2].y), f2bf(fB[pi][2].z), f2bf(fB[pi][2].w)};
    u16 e3[4] = {f2bf(fB[pi][3].x), f2bf(fB[pi][3].y), f2bf(fB[pi][3].z), f2bf(fB[pi][3].w)};
#pragma unroll
    for (int nn = 0; nn < 4; ++nn) {
      const int row = ng * 4 + nn;
      const int cb = (kg * 8) ^ swz(row);
      *(uint2*)(smem + 49152 + row * 128 + cb) = make_uint2(pk2(e0[nn], e1[nn]), pk2(e2[nn], e3[nn]));
    }
  }
}

__device__ __forceinline__ void conv_a_glds(char* smem, const u16* __restrict__ wbf,
                                            int obase, int kb, int w, int l, int buf) {
#pragma unroll
  for (int i = 0; i < 6; ++i) {
    const int grp = i * 4 + w;
    const int row = grp * 8 + (l >> 3);
    const int cb = ((l & 7) * 16) ^ swz(row);
    const char* src = (const char*)wbf + (size_t)(obase + row) * 384 + kb * 2 + cb;
    gl_lds16(src, smem + buf * 24576 + grp * 1024);
  }
}

__global__ __launch_bounds__(256) void conv_mfma_kernel(
    const float* __restrict__ x, const u16* __restrict__ wbf, u16* __restrict__ pre) {
  __shared__ char smem[65536];
  const int bid = blockIdx.x;                      // 3072 blocks
  const int id = (bid & 7) * 384 + (bid >> 3);     // bijective XCD chunk
  const int b = id / 384;
  const int rr = id % 384;
  const int nbase = (rr / 3) * 128;
  const int obase = (rr % 3) * 192;
  const int tid = threadIdx.x;
  const int w = tid >> 6, l = tid & 63;
  const int wr = w >> 1, wc = w & 1;

  f32x4 acc[6][4];
#pragma unroll
  for (int m = 0; m < 6; ++m)
#pragma unroll
    for (int nf = 0; nf < 4; ++nf) acc[m][nf] = (f32x4)0.f;

  float4 fB[2][4];
  // prologue: stage tile 0
  conv_b_load(x, b, nbase, 0, tid, fB);
  conv_a_glds(smem, wbf, obase, 0, w, l, 0);
  conv_b_write(smem, tid, fB);
  __syncthreads();

  for (int t = 0; t < 3; ++t) {
    const int cur = t & 1;
    const int nxt = cur ^ 1;
    if (t < 2) {
      conv_b_load(x, b, nbase, (t + 1) * 64, tid, fB);    // issue early
      conv_a_glds(smem, wbf, obase, (t + 1) * 64, w, l, nxt);
    }
#pragma unroll
    for (int kk = 0; kk < 2; ++kk) {
      s16x8 a[6], bv[4];
      const int cbk = kk * 64 + (l >> 4) * 16;
#pragma unroll
      for (int m = 0; m < 6; ++m) {
        const int rowA = wr * 96 + m * 16 + (l & 15);
        a[m] = *(const s16x8*)(smem + cur * 24576 + rowA * 128 + (cbk ^ swz(rowA)));
      }
#pragma unroll
      for (int nf = 0; nf < 4; ++nf) {
        const int rowB = wc * 64 + nf * 16 + (l & 15);
        bv[nf] = *(const s16x8*)(smem + 49152 + rowB * 128 + (cbk ^ swz(rowB)));
      }
#pragma unroll
      for (int m = 0; m < 6; ++m)
#pragma unroll
        for (int nf = 0; nf < 4; ++nf)
          acc[m][nf] = __builtin_amdgcn_mfma_f32_16x16x32_bf16(a[m], bv[nf], acc[m][nf], 0, 0, 0);
    }
    __syncthreads();             // all waves done reading B
    if (t < 2) {
      conv_b_write(smem, tid, fB);  // write late
      __syncthreads();           // new B (and A[nxt]) ready
    }
  }
  // epilogue: per-wave LDS transpose ([16][72] u16), then 16B stores.
  u16* cw = (u16*)(smem) + w * 16 * 72;
#pragma unroll
  for (int m = 0; m < 6; ++m) {
#pragma unroll
    for (int nf = 0; nf < 4; ++nf)
#pragma unroll
      for (int r = 0; r < 4; ++r)
        cw[((l >> 4) * 4 + r) * 72 + nf * 16 + (l & 15)] = f2bf(acc[m][nf][r]);
#pragma unroll
    for (int p = 0; p < 2; ++p) {
      const int chunk = p * 64 + l;
      const int row = chunk >> 3, cg = chunk & 7;
      uint4 v = *(const uint4*)(cw + row * 72 + cg * 8);
      const int o = obase + wr * 96 + m * 16 + row;
      const int n = nbase + wc * 64 + cg * 8;
      *(uint4*)(pre + (((size_t)b * NC3 + o) << 14) + n) = v;
    }
  }
}

// ---------------------------------------------------------------------------
// depthwise 3x3 (8 px/thread) + fused sum-of-squares for q,k planes.
// x-edges via cross-lane shfl (no scalar loads).
// ---------------------------------------------------------------------------
__global__ __launch_bounds__(256) void dwconv_kernel(
    const u16* __restrict__ in, const float* __restrict__ wdw, u16* __restrict__ out,
    float* __restrict__ norms2, const int mod) {
  const size_t t = (size_t)blockIdx.x * 256 + threadIdx.x;
  const int tid = threadIdx.x;
  const int l = tid & 63;
  const int xc = (int)(t & 15);
  const int yy = (int)((t >> 4) & 127);
  const int bc = (int)(t >> 11);
  const int c = bc % NC3;
  const int b = bc / NC3;
  const u16* p = in + ((size_t)bc << 14);
  const float* wc = wdw + c * 9;
  const int x0 = xc * 8;

  float a[3][10];
#pragma unroll
  for (int r = 0; r < 3; ++r) {
    const int y2 = yy + r - 1;
    if ((unsigned)y2 < 128u) {
      const u16* row = p + (y2 << 7);
      uint4 v = *(const uint4*)(row + x0);
      a[r][1] = bf2f(v.x & 0xffff); a[r][2] = bf2f(v.x >> 16);
      a[r][3] = bf2f(v.y & 0xffff); a[r][4] = bf2f(v.y >> 16);
      a[r][5] = bf2f(v.z & 0xffff); a[r][6] = bf2f(v.z >> 16);
      a[r][7] = bf2f(v.w & 0xffff); a[r][8] = bf2f(v.w >> 16);
    } else {
#pragma unroll
      for (int j = 1; j < 9; ++j) a[r][j] = 0.f;
    }
    const float lf = __shfl(a[r][8], (l - 1) & 63, 64);
    const float rt = __shfl(a[r][1], (l + 1) & 63, 64);
    a[r][0] = (xc > 0) ? lf : 0.f;
    a[r][9] = (xc < 15) ? rt : 0.f;
  }
  const float w00 = wc[0], w01 = wc[1], w02 = wc[2];
  const float w10 = wc[3], w11 = wc[4], w12 = wc[5];
  const float w20 = wc[6], w21 = wc[7], w22 = wc[8];
  u16 o[8];
  float ssq = 0.f;
#pragma unroll
  for (int j = 0; j < 8; ++j) {
    float s = a[0][j] * w00;
    s = fmaf(a[0][j + 1], w01, s);
    s = fmaf(a[0][j + 2], w02, s);
    s = fmaf(a[1][j], w10, s);
    s = fmaf(a[1][j + 1], w11, s);
    s = fmaf(a[1][j + 2], w12, s);
    s = fmaf(a[2][j], w20, s);
    s = fmaf(a[2][j + 1], w21, s);
    s = fmaf(a[2][j + 2], w22, s);
    ssq = fmaf(s, s, ssq);
    o[j] = f2bf(s);
  }
  *(uint4*)(out + (t << 3)) =
      make_uint4(pk2(o[0], o[1]), pk2(o[2], o[3]), pk2(o[4], o[5]), pk2(o[6], o[7]));

  if (c < 384) {
#pragma unroll
    for (int off = 32; off > 0; off >>= 1) ssq += __shfl_down(ssq, off, 64);
    __shared__ float red[4];
    if ((tid & 63) == 0) red[tid >> 6] = ssq;
    __syncthreads();
    if (tid == 0) {
      const int tt = (c < 192) ? mod : 2 + mod;
      atomicAdd(&norms2[(tt * NB + b) * NCH + (c % NCH)], red[0] + red[1] + red[2] + red[3]);
    }
  }
}

// ---------------------------------------------------------------------------
// Gram via MFMA, fragments direct from global (NT: contraction over n).
// ---------------------------------------------------------------------------
__global__ __launch_bounds__(256) void gram_mfma_kernel(
    const u16* __restrict__ qkv1, const u16* __restrict__ qkv2, float* __restrict__ gp) {
  const int nc = blockIdx.x, h = blockIdx.y, b = blockIdx.z;
  const int tid = threadIdx.x;
  const int w = tid >> 6, l = tid & 63;

  const u16* qp[3];
  const u16* kp[3];
#pragma unroll
  for (int m = 0; m < 3; ++m) {
    const int rq = m * 16 + (l & 15);
    const int cc = h * 24 + (rq < 24 ? rq : rq - 24);
    const u16* basep = (rq < 24) ? qkv1 : qkv2;
    qp[m] = basep + (((size_t)b * NC3 + cc) << 14);
    kp[m] = basep + (((size_t)b * NC3 + 192 + cc) << 14);
  }
  const int kbase = nc * 1024 + w * 256 + (l >> 4) * 8;

  f32x4 acc[3][3];
#pragma unroll
  for (int m = 0; m < 3; ++m)
#pragma unroll
    for (int nf = 0; nf < 3; ++nf) acc[m][nf] = (f32x4)0.f;

  for (int t = 0; t < 8; ++t) {
    const int ko = kbase + t * 32;
    s16x8 a[3], bv[3];
#pragma unroll
    for (int m = 0; m < 3; ++m) {
      a[m] = *(const s16x8*)(qp[m] + ko);
      bv[m] = *(const s16x8*)(kp[m] + ko);
    }
#pragma unroll
    for (int m = 0; m < 3; ++m)
#pragma unroll
      for (int nf = 0; nf < 3; ++nf)
        acc[m][nf] = __builtin_amdgcn_mfma_f32_16x16x32_bf16(a[m], bv[nf], acc[m][nf], 0, 0, 0);
  }

  __shared__ float red[4][48][48];
#pragma unroll
  for (int m = 0; m < 3; ++m)
#pragma unroll
    for (int nf = 0; nf < 3; ++nf)
#pragma unroll
      for (int r = 0; r < 4; ++r)
        red[w][m * 16 + (l >> 4) * 4 + r][nf * 16 + (l & 15)] = acc[m][nf][r];
  __syncthreads();
  float* dst = gp + ((((size_t)b * 8 + h) * 16 + nc) * 2304);
  for (int e = tid; e < 2304; e += 256) {
    const int rr = e / 48, cc = e % 48;
    dst[e] = red[0][rr][cc] + red[1][rr][cc] + red[2][rr][cc] + red[3][rr][cc];
  }
}

__global__ __launch_bounds__(256) void gram_reduce_kernel(
    const float* __restrict__ gp, float* __restrict__ G) {
  const int bh = blockIdx.x;
  for (int e = threadIdx.x; e < 2304; e += 256) {
    float s = 0.f;
    for (int p = 0; p < 16; ++p) s += gp[((size_t)bh * 16 + p) * 2304 + e];
    G[(size_t)bh * 2304 + e] = s;
  }
}

// ---------------------------------------------------------------------------
// softmax (4x 24x24 per b,h) + fused weights, bf16 output
// ---------------------------------------------------------------------------
__global__ __launch_bounds__(256) void softmax_wcat_kernel(
    const float* __restrict__ G, const float* __restrict__ norms2,
    const float* __restrict__ temperature, const float* __restrict__ beta,
    const float* __restrict__ wproj, u16* __restrict__ Wcat) {
  const int bh = blockIdx.x;
  const int b = bh >> 3, h = bh & 7;
  __shared__ float sm[4][24][24];
  __shared__ float nrm[4][24];
  const int tid = threadIdx.x;
  if (tid < 96) {
    int t = tid / 24, ci = tid % 24;
    nrm[t][ci] = fmaxf(sqrtf(norms2[(t * NB + b) * NCH + h * 24 + ci]), 1e-12f);
  }
  __syncthreads();
  const float T = temperature[h];
  const float sigB = 1.f / (1.f + expf(-beta[0]));
  if (tid < 96) {
    const int m = tid / 24, r = tid % 24;
    const float* Gb = G + (size_t)bh * 2304;
    const int gr = (m >= 2) ? 24 + r : r;
    const int gc0 = (m == 1 || m == 2) ? 24 : 0;
    const float* qn = (m >= 2) ? nrm[1] : nrm[0];
    const float* kn = (m == 1 || m == 2) ? nrm[3] : nrm[2];
    const float sign = (m == 0 || m == 2) ? 1.f : -1.f;
    const float qs = sign * T / qn[r];
    float L[24], mx = -1e30f;
#pragma unroll
    for (int cc = 0; cc < 24; ++cc) {
      L[cc] = Gb[gr * 48 + gc0 + cc] * qs / kn[cc];
      mx = fmaxf(mx, L[cc]);
    }
    float ssum = 0.f;
#pragma unroll
    for (int cc = 0; cc < 24; ++cc) {
      L[cc] = expf(L[cc] - mx);
      ssum += L[cc];
    }
    const float inv = 1.f / ssum;
#pragma unroll
    for (int cc = 0; cc < 24; ++cc) sm[m][r][cc] = L[cc] * inv;
  }
  __syncthreads();
  for (int e = tid; e < 384 * 48; e += 256) {
    const int o = e / 48, dc = e % 48;
    const int part = dc / 24, d = dc % 24;
    const int oc = (o < 192) ? o : o - 192;
    int m;
    float scale;
    if (o < 192) { m = part ? 1 : 0; scale = part ? 1.f : sigB; }
    else         { m = part ? 2 : 3; scale = part ? sigB : 1.f; }
    float s = 0.f;
#pragma unroll
    for (int ci = 0; ci < 24; ++ci) s += wproj[oc * 192 + h * 24 + ci] * sm[m][ci][d];
    Wcat[((size_t)b * 384 + o) * 384 + part * 192 + h * 24 + d] = f2bf(s * scale);
  }
}

// ---------------------------------------------------------------------------
// final GEMM MFMA, 2-phase pipelined full double-buffer.
// LDS: A0 @0, A1 @16384, B0 @32768, B1 @49152 = 64 KB.
// ---------------------------------------------------------------------------
__device__ __forceinline__ void fin_b_load(const u16* __restrict__ qkv1,
                                           const u16* __restrict__ qkv2,
                                           int b, int nbase, int kb, int tid,
                                           uint2 (&fV)[2][4]) {
  const u16* vbase = (kb < 192) ? qkv1 + (((size_t)b * NC3 + 384 + kb) << 14)
                                : qkv2 + (((size_t)b * NC3 + 384 + kb - 192) << 14);
#pragma unroll
  for (int pi = 0; pi < 2; ++pi) {
    const int p = pi * 256 + tid;
    const int ng = p & 31, kg = p >> 5;
    const u16* vr = vbase + (((size_t)kg * 4) << 14) + nbase + ng * 4;
    fV[pi][0] = *(const uint2*)(vr);
    fV[pi][1] = *(const uint2*)(vr + NHW);
    fV[pi][2] = *(const uint2*)(vr + 2 * NHW);
    fV[pi][3] = *(const uint2*)(vr + 3 * NHW);
  }
}

__device__ __forceinline__ void fin_b_write(char* smem, int tid, int buf,
                                            const uint2 (&fV)[2][4]) {
#pragma unroll
  for (int pi = 0; pi < 2; ++pi) {
    const int p = pi * 256 + tid;
    const int ng = p & 31, kg = p >> 5;
    u16 e0[4] = {(u16)(fV[pi][0].x & 0xffff), (u16)(fV[pi][0].x >> 16), (u16)(fV[pi][0].y & 0xffff), (u16)(fV[pi][0].y >> 16)};
    u16 e1[4] = {(u16)(fV[pi][1].x & 0xffff), (u16)(fV[pi][1].x >> 16), (u16)(fV[pi][1].y & 0xffff), (u16)(fV[pi][1].y >> 16)};
    u16 e2[4] = {(u16)(fV[pi][2].x & 0xffff), (u16)(fV[pi][2].x >> 16), (u16)(fV[pi][2].y & 0xffff), (u16)(fV[pi][2].y >> 16)};
    u16 e3[4] = {(u16)(fV[pi][3].x & 0xffff), (u16)(fV[pi][3].x >> 16), (u16)(fV[pi][3].y & 0xffff), (u16)(fV[pi][3].y >> 16)};
#pragma unroll
    for (int nn = 0; nn < 4; ++nn) {
      const int row = ng * 4 + nn;
      const int cb = (kg * 8) ^ swz(row);
      *(uint2*)(smem + 32768 + buf * 16384 + row * 128 + cb) =
          make_uint2(pk2(e0[nn], e1[nn]), pk2(e2[nn], e3[nn]));
    }
  }
}

__device__ __forceinline__ void fin_a_glds(char* smem, const u16* __restrict__ Wcat,
                                           int b, int obase, int kb, int w, int l, int buf) {
#pragma unroll
  for (int i = 0; i < 4; ++i) {
    const int grp = i * 4 + w;
    const int row = grp * 8 + (l >> 3);
    const int cb = ((l & 7) * 16) ^ swz(row);
    const char* src = (const char*)Wcat + ((size_t)b * 384 + obase + row) * 768 + kb * 2 + cb;
    gl_lds16(src, smem + buf * 16384 + grp * 1024);
  }
}

__global__ __launch_bounds__(256) void final_mfma_kernel(
    const u16* __restrict__ qkv1, const u16* __restrict__ qkv2,
    const u16* __restrict__ Wcat, float* __restrict__ out) {
  __shared__ char smem[65536];
  const int bid = blockIdx.x;                      // 3072 blocks
  const int id = (bid & 7) * 384 + (bid >> 3);
  const int b = id / 384;
  const int rr2 = id % 384;
  const int nbase = (rr2 / 3) * 128;
  const int obase = (rr2 % 3) * 128;
  const int tid = threadIdx.x;
  const int w = tid >> 6, l = tid & 63;
  const int wr = w >> 1, wc = w & 1;

  f32x4 acc[4][4];
#pragma unroll
  for (int m = 0; m < 4; ++m)
#pragma unroll
    for (int nf = 0; nf < 4; ++nf) acc[m][nf] = (f32x4)0.f;

  uint2 fV[2][4];
  fin_b_load(qkv1, qkv2, b, nbase, 0, tid, fV);
  fin_a_glds(smem, Wcat, b, obase, 0, w, l, 0);
  fin_b_write(smem, tid, 0, fV);
  __syncthreads();

  for (int t = 0; t < 6; ++t) {
    const int cur = t & 1;
    const int nxt = cur ^ 1;
    if (t < 5) {
      fin_b_load(qkv1, qkv2, b, nbase, (t + 1) * 64, tid, fV);  // issue early
      fin_a_glds(smem, Wcat, b, obase, (t + 1) * 64, w, l, nxt);
    }
#pragma unroll
    for (int kk = 0; kk < 2; ++kk) {
      s16x8 a[4], bv[4];
      const int cbk = kk * 64 + (l >> 4) * 16;
#pragma unroll
      for (int m = 0; m < 4; ++m) {
        const int rowA = wr * 64 + m * 16 + (l & 15);
        a[m] = *(const s16x8*)(smem + cur * 16384 + rowA * 128 + (cbk ^ swz(rowA)));
      }
#pragma unroll
      for (int nf = 0; nf < 4; ++nf) {
        const int rowB = wc * 64 + nf * 16 + (l & 15);
        bv[nf] = *(const s16x8*)(smem + 32768 + cur * 16384 + rowB * 128 + (cbk ^ swz(rowB)));
      }
#pragma unroll
      for (int m = 0; m < 4; ++m)
#pragma unroll
        for (int nf = 0; nf < 4; ++nf)
          acc[m][nf] = __builtin_amdgcn_mfma_f32_16x16x32_bf16(a[m], bv[nf], acc[m][nf], 0, 0, 0);
    }
    if (t < 5) fin_b_write(smem, tid, nxt, fV);    // write late
    __syncthreads();
  }
  // epilogue: per-wave LDS transpose ([16][68] f32), then float4 stores.
  float* cw = (float*)(smem + w * 4352);
#pragma unroll
  for (int m = 0; m < 4; ++m) {
#pragma unroll
    for (int nf = 0; nf < 4; ++nf)
#pragma unroll
      for (int r = 0; r < 4; ++r)
        cw[((l >> 4) * 4 + r) * 68 + nf * 16 + (l & 15)] = acc[m][nf][r];
#pragma unroll
    for (int p = 0; p < 4; ++p) {
      const int chunk = p * 64 + l;
      const int row = chunk >> 4, cg = chunk & 15;
      float4 v = *(const float4*)(cw + row * 68 + cg * 4);
      const int o = obase + wr * 64 + m * 16 + row;
      const int n = nbase + wc * 64 + cg * 4;
      float* dst = (o < 192) ? out + (((size_t)b * NCH + o) << 14) + n
                             : out + 25165824 + (((size_t)b * NCH + o - 192) << 14) + n;
      *(float4*)dst = v;
    }
  }
}

// ---------------------------------------------------------------------------
extern "C" void kernel_launch(void* const* d_in, const int* in_sizes, int n_in,
                              void* d_out, int out_size, void* d_ws, size_t ws_size,
                              hipStream_t stream) {
  (void)in_sizes; (void)n_in; (void)out_size; (void)ws_size;
  const float* x1 = (const float*)d_in[0];
  const float* x2 = (const float*)d_in[1];
  const float* w_qkv1 = (const float*)d_in[2];
  const float* w_dw1 = (const float*)d_in[3];
  const float* w_qkv2 = (const float*)d_in[4];
  const float* w_dw2 = (const float*)d_in[5];
  const float* w_proj = (const float*)d_in[6];
  const float* temperature = (const float*)d_in[7];
  const float* beta = (const float*)d_in[8];
  float* out = (float*)d_out;

  char* wsb = (char*)d_ws;
  u16* pre = (u16*)(wsb);                       // 150,994,944
  u16* qkv1 = (u16*)(wsb + 150994944);          // 150,994,944
  u16* qkv2 = (u16*)(wsb + 301989888);          // 150,994,944
  u16* wbf1 = (u16*)(wsb + 452984832);          // 221,184
  u16* wbf2 = (u16*)(wsb + 453206016);          // 221,184
  float* norms2 = (float*)(wsb + 453427200);    // 24,576
  float* G = (float*)(wsb + 453451776);         // 589,824
  u16* WcatBf = (u16*)(wsb + 454041600);        // 2,359,296
  float* gp = (float*)(wsb + 456400896);        // 9,437,184  -> end 465,838,080

  const int dwblocks = (int)(((size_t)NB * NC3 * NHW) / (256 * 8));

  wcast_kernel<<<(NC3 * NCH + 255) / 256, 256, 0, stream>>>(w_qkv1, w_qkv2, wbf1, wbf2, norms2);
  conv_mfma_kernel<<<3072, 256, 0, stream>>>(x1, wbf1, pre);
  dwconv_kernel<<<dwblocks, 256, 0, stream>>>(pre, w_dw1, qkv1, norms2, 0);
  conv_mfma_kernel<<<3072, 256, 0, stream>>>(x2, wbf2, pre);
  dwconv_kernel<<<dwblocks, 256, 0, stream>>>(pre, w_dw2, qkv2, norms2, 1);
  gram_mfma_kernel<<<dim3(16, NHEADS, NB), 256, 0, stream>>>(qkv1, qkv2, gp);
  gram_reduce_kernel<<<NB * NHEADS, 256, 0, stream>>>(gp, G);
  softmax_wcat_kernel<<<NB * NHEADS, 256, 0, stream>>>(G, norms2, temperature, beta, w_proj, WcatBf);
  final_mfma_kernel<<<3072, 256, 0, stream>>>(qkv1, qkv2, WcatBf, out);
}